// Round 1
// baseline (4398.080 us; speedup 1.0000x reference)
//
#include <hip/hip_runtime.h>
#include <hip/hip_bf16.h>
#include <cstdio>

#define U_N 100000
#define I_N 50000
#define H_DIM 128
#define E_N 600000
#define EL_N 200000

typedef __attribute__((ext_vector_type(8))) short bh8;
typedef __attribute__((ext_vector_type(4))) float f32x4;

// fp32 -> bf16 (RNE), self-contained
__device__ inline short f2b(float f) {
  unsigned u = __builtin_bit_cast(unsigned, f);
  u += 0x7fffu + ((u >> 16) & 1u);
  return (short)(u >> 16);
}

// ---------------- degree count (shared by both layers) ----------------
__global__ __launch_bounds__(256) void count_deg(const int* __restrict__ eui,
                                                 int* __restrict__ cu,
                                                 int* __restrict__ ci) {
  int t = blockIdx.x * 256 + threadIdx.x;
  if (t >= E_N) return;
  atomicAdd(&cu[eui[t]], 1);          // row0: users
  atomicAdd(&ci[eui[E_N + t]], 1);    // row1: items
}

// ---------------- weight prep: W2t[col][k], k<128 -> w_l[k][col], else w_r ----
__global__ __launch_bounds__(256) void prep_w(const float* __restrict__ wl,
                                              const float* __restrict__ wr,
                                              short* __restrict__ W2) {
  int t = blockIdx.x * 256 + threadIdx.x;  // 128*256 = 32768
  int col = t >> 8, k = t & 255;
  float v = (k < 128) ? wl[k * 128 + col] : wr[(k - 128) * 128 + col];
  W2[col * 256 + k] = f2b(v);
}

// ---------------- edge-parallel scatter sum (mean numerator) ----------------
__global__ __launch_bounds__(256) void scatter_sum(const int* __restrict__ src,
                                                   const int* __restrict__ dst,
                                                   const int* __restrict__ nid,
                                                   const float* __restrict__ xsrc,
                                                   float* __restrict__ agg) {
  long t = (long)blockIdx.x * 256 + threadIdx.x;
  int e = (int)(t >> 5);
  if (e >= E_N) return;
  int lane = (int)(t & 31);
  int s = src[e];
  if (nid) s = nid[s];
  int d = dst[e];
  float4 v = *(const float4*)(xsrc + (size_t)s * H_DIM + lane * 4);
  float* a = agg + (size_t)d * H_DIM + lane * 4;
  unsafeAtomicAdd(a + 0, v.x);
  unsafeAtomicAdd(a + 1, v.y);
  unsafeAtomicAdd(a + 2, v.z);
  unsafeAtomicAdd(a + 3, v.w);
}

// ---------------- fused SAGE linear: out = act( (agg/cnt)@w_l + x@w_r + b ) --
// A2[n][k] = k<128 ? mean[n][k] : x[n][k-128]  (built on the fly, bf16)
// W2 (global, bf16): [col][k] 128x256 ; staged to LDS with xor-swizzle
__global__ __launch_bounds__(256) void sage_gemm(const float* __restrict__ agg,
                                                 const int* __restrict__ cnt,
                                                 const float* __restrict__ x,
                                                 const int* __restrict__ nid,
                                                 const short* __restrict__ W2,
                                                 const float* __restrict__ bias,
                                                 float* __restrict__ out,
                                                 int N, int relu) {
  __shared__ short wlds[128 * 256];  // 64 KiB
  const int tid = threadIdx.x;
  // stage weights: granule g (8 bf16) of col stored at position g ^ (col&15)
  for (int c = tid; c < 4096; c += 256) {
    int col = c >> 5, g = c & 31;
    uint4 v = *(const uint4*)(W2 + col * 256 + g * 8);
    *(uint4*)(&wlds[col * 256 + ((g ^ (col & 15)) * 8)]) = v;
  }
  __syncthreads();

  const int lane = tid & 63;
  const int wave = tid >> 6;
  const int q = lane >> 4;       // quad
  const int n16 = lane & 15;
  const int rowbase = blockIdx.x * 128 + wave * 32;

  const float* aptr[2];
  const float* xptr[2];
  float invc[2];
  for (int g = 0; g < 2; ++g) {
    int row = rowbase + g * 16 + n16;
    int rr = row < N ? row : 0;
    aptr[g] = agg + (size_t)rr * H_DIM + q * 8;
    int xr = nid ? nid[rr] : rr;
    xptr[g] = x + (size_t)xr * H_DIM + q * 8;
    int c0 = cnt[rr];
    invc[g] = 1.0f / (float)(c0 > 0 ? c0 : 1);
  }

  f32x4 acc[2][8] = {};

  for (int kt = 0; kt < 8; ++kt) {
    const int k0 = kt * 32;
    bh8 afrag[2];
    for (int g = 0; g < 2; ++g) {
      const float* p = (kt < 4) ? (aptr[g] + k0) : (xptr[g] + (k0 - 128));
      float4 v0 = *(const float4*)(p);
      float4 v1 = *(const float4*)(p + 4);
      float s = (kt < 4) ? invc[g] : 1.0f;
      bh8 a;
      a[0] = f2b(v0.x * s); a[1] = f2b(v0.y * s);
      a[2] = f2b(v0.z * s); a[3] = f2b(v0.w * s);
      a[4] = f2b(v1.x * s); a[5] = f2b(v1.y * s);
      a[6] = f2b(v1.z * s); a[7] = f2b(v1.w * s);
      afrag[g] = a;
    }
    const int swz = ((kt * 4 + q) ^ n16) * 8;
    for (int c = 0; c < 8; ++c) {
      bh8 b = *(const bh8*)(&wlds[(c * 16 + n16) * 256 + swz]);
      acc[0][c] = __builtin_amdgcn_mfma_f32_16x16x32_bf16(afrag[0], b, acc[0][c], 0, 0, 0);
      acc[1][c] = __builtin_amdgcn_mfma_f32_16x16x32_bf16(afrag[1], b, acc[1][c], 0, 0, 0);
    }
  }

  float bcol[8];
  for (int c = 0; c < 8; ++c) bcol[c] = bias[c * 16 + n16];

  for (int g = 0; g < 2; ++g) {
    for (int r = 0; r < 4; ++r) {
      int row = rowbase + g * 16 + q * 4 + r;
      if (row >= N) continue;
      float* orow = out + (size_t)row * H_DIM;
      for (int c = 0; c < 8; ++c) {
        float v = acc[g][c][r] + bcol[c];
        if (relu) v = v > 0.0f ? v : 0.0f;
        orow[c * 16 + n16] = v;
      }
    }
  }
}

// ---------------- final edge dot product ----------------
__global__ __launch_bounds__(256) void final_dot(const int* __restrict__ lbl,
                                                 const float* __restrict__ u2,
                                                 const float* __restrict__ i2,
                                                 float* __restrict__ out) {
  long t = (long)blockIdx.x * 256 + threadIdx.x;
  int e = (int)(t >> 5);
  if (e >= EL_N) return;
  int lane = (int)(t & 31);
  int lu = lbl[e];
  int li = lbl[EL_N + e];
  float4 a = *(const float4*)(u2 + (size_t)lu * H_DIM + lane * 4);
  float4 b = *(const float4*)(i2 + (size_t)li * H_DIM + lane * 4);
  float p = a.x * b.x + a.y * b.y + a.z * b.z + a.w * b.w;
  for (int off = 16; off > 0; off >>= 1) p += __shfl_down(p, off, 32);
  if (lane == 0) out[e] = p;
}

extern "C" void kernel_launch(void* const* d_in, const int* in_sizes, int n_in,
                              void* d_out, int out_size, void* d_ws, size_t ws_size,
                              hipStream_t stream) {
  const float* user_emb = (const float*)d_in[0];
  const float* item_emb = (const float*)d_in[1];
  const float* w1_ui_l = (const float*)d_in[2];
  const float* w1_ui_r = (const float*)d_in[3];
  const float* w1_iu_l = (const float*)d_in[4];
  const float* w1_iu_r = (const float*)d_in[5];
  const float* w2_ui_l = (const float*)d_in[6];
  const float* w2_ui_r = (const float*)d_in[7];
  const float* w2_iu_l = (const float*)d_in[8];
  const float* w2_iu_r = (const float*)d_in[9];
  const float* b1_ui = (const float*)d_in[10];
  const float* b1_iu = (const float*)d_in[11];
  const float* b2_ui = (const float*)d_in[12];
  const float* b2_iu = (const float*)d_in[13];
  const int* unid = (const int*)d_in[14];
  const int* inid = (const int*)d_in[15];
  const int* e_ui = (const int*)d_in[16];  // row0 users, row1 items
  const int* e_iu = (const int*)d_in[17];  // row0 items, row1 users
  const int* elbl = (const int*)d_in[18];  // row0 users, row1 items
  float* out = (float*)d_out;

  char* ws = (char*)d_ws;
  size_t o = 0;
  auto alloc = [&](size_t bytes) {
    char* p = ws + o;
    o = (o + bytes + 255) & ~(size_t)255;
    return p;
  };
  int* cnt_u = (int*)alloc((size_t)U_N * 4);
  int* cnt_i = (int*)alloc((size_t)I_N * 4);
  size_t agg_off = o;
  float* agg_u = (float*)alloc((size_t)U_N * H_DIM * 4);
  float* agg_i = (float*)alloc((size_t)I_N * H_DIM * 4);
  size_t zero_end = o;
  float* h1_u = (float*)alloc((size_t)U_N * H_DIM * 4);
  float* h1_i = (float*)alloc((size_t)I_N * H_DIM * 4);
  float* h2_u = (float*)alloc((size_t)U_N * H_DIM * 4);
  float* h2_i = (float*)alloc((size_t)I_N * H_DIM * 4);
  short* W2_1u = (short*)alloc(128 * 256 * 2);
  short* W2_1i = (short*)alloc(128 * 256 * 2);
  short* W2_2u = (short*)alloc(128 * 256 * 2);
  short* W2_2i = (short*)alloc(128 * 256 * 2);
  if (o > ws_size) {
    fprintf(stderr, "kernel_launch: ws too small, need %zu have %zu\n", o, ws_size);
    return;
  }

  // zero cnt + agg
  hipMemsetAsync(d_ws, 0, zero_end, stream);
  count_deg<<<(E_N + 255) / 256, 256, 0, stream>>>(e_ui, cnt_u, cnt_i);
  prep_w<<<128, 256, 0, stream>>>(w1_iu_l, w1_iu_r, W2_1u);
  prep_w<<<128, 256, 0, stream>>>(w1_ui_l, w1_ui_r, W2_1i);
  prep_w<<<128, 256, 0, stream>>>(w2_iu_l, w2_iu_r, W2_2u);
  prep_w<<<128, 256, 0, stream>>>(w2_ui_l, w2_ui_r, W2_2i);

  const int sblocks = (E_N * 32) / 256;  // 75000
  // layer 1 aggregation: users <- items, items <- users
  scatter_sum<<<sblocks, 256, 0, stream>>>(e_iu, e_iu + E_N, inid, item_emb, agg_u);
  scatter_sum<<<sblocks, 256, 0, stream>>>(e_ui, e_ui + E_N, unid, user_emb, agg_i);

  sage_gemm<<<(U_N + 127) / 128, 256, 0, stream>>>(agg_u, cnt_u, user_emb, unid,
                                                   W2_1u, b1_iu, h1_u, U_N, 1);
  sage_gemm<<<(I_N + 127) / 128, 256, 0, stream>>>(agg_i, cnt_i, item_emb, inid,
                                                   W2_1i, b1_ui, h1_i, I_N, 1);

  // re-zero agg for layer 2
  hipMemsetAsync(ws + agg_off, 0, zero_end - agg_off, stream);
  scatter_sum<<<sblocks, 256, 0, stream>>>(e_iu, e_iu + E_N, nullptr, h1_i, agg_u);
  scatter_sum<<<sblocks, 256, 0, stream>>>(e_ui, e_ui + E_N, nullptr, h1_u, agg_i);

  sage_gemm<<<(U_N + 127) / 128, 256, 0, stream>>>(agg_u, cnt_u, h1_u, nullptr,
                                                   W2_2u, b2_iu, h2_u, U_N, 0);
  sage_gemm<<<(I_N + 127) / 128, 256, 0, stream>>>(agg_i, cnt_i, h1_i, nullptr,
                                                   W2_2i, b2_ui, h2_i, I_N, 0);

  final_dot<<<(EL_N * 32) / 256, 256, 0, stream>>>(elbl, h2_u, h2_i, out);
}

// Round 2
// 957.886 us; speedup vs baseline: 4.5914x; 4.5914x over previous
//
#include <hip/hip_runtime.h>
#include <hip/hip_bf16.h>
#include <cstdio>

#define U_N 100000
#define I_N 50000
#define H_DIM 128
#define E_N 600000
#define EL_N 200000

typedef __attribute__((ext_vector_type(8))) short bh8;
typedef __attribute__((ext_vector_type(4))) float f32x4;

// fp32 -> bf16 (RNE), self-contained
__device__ inline short f2b(float f) {
  unsigned u = __builtin_bit_cast(unsigned, f);
  u += 0x7fffu + ((u >> 16) & 1u);
  return (short)(u >> 16);
}

// ---------------- degree count (shared by both layers) ----------------
__global__ __launch_bounds__(256) void count_deg(const int* __restrict__ eui,
                                                 int* __restrict__ cu,
                                                 int* __restrict__ ci) {
  int t = blockIdx.x * 256 + threadIdx.x;
  if (t >= E_N) return;
  atomicAdd(&cu[eui[t]], 1);          // row0: users
  atomicAdd(&ci[eui[E_N + t]], 1);    // row1: items
}

// ---------------- exclusive scan (single block, 1024 thr) -> off & cur ------
__global__ __launch_bounds__(1024) void scan_off(const int* __restrict__ cnt,
                                                 int* __restrict__ off,
                                                 int* __restrict__ cur, int n) {
  __shared__ int sums[1024];
  const int t = threadIdx.x;
  const int chunk = (n + 1023) >> 10;
  int lo = t * chunk, hi = lo + chunk;
  if (lo > n) lo = n;
  if (hi > n) hi = n;
  int s = 0;
  for (int i = lo; i < hi; ++i) s += cnt[i];
  sums[t] = s;
  __syncthreads();
  for (int d = 1; d < 1024; d <<= 1) {
    int v = (t >= d) ? sums[t - d] : 0;
    __syncthreads();
    sums[t] += v;
    __syncthreads();
  }
  int base = (t == 0) ? 0 : sums[t - 1];
  for (int i = lo; i < hi; ++i) {
    off[i] = base;
    cur[i] = base;
    base += cnt[i];
  }
}

// ---------------- CSR fill: csr[pos] = src, grouped by dst ------------------
__global__ __launch_bounds__(256) void fill_csr(const int* __restrict__ dst,
                                                const int* __restrict__ src,
                                                int* __restrict__ cur,
                                                int* __restrict__ csr) {
  int t = blockIdx.x * 256 + threadIdx.x;
  if (t >= E_N) return;
  int pos = atomicAdd(&cur[dst[t]], 1);
  csr[pos] = src[t];
}

// ---------------- gather-aggregate: agg[d] = sum_{j in N(d)} x[j] -----------
// half-wave (32 lanes) per destination node; 16B/lane contiguous reads
__global__ __launch_bounds__(256) void gather_sum(const int* __restrict__ off,
                                                  const int* __restrict__ cnt,
                                                  const int* __restrict__ csr,
                                                  const int* __restrict__ nid,
                                                  const float* __restrict__ xsrc,
                                                  float* __restrict__ agg, int N) {
  long t = (long)blockIdx.x * 256 + threadIdx.x;
  int node = (int)(t >> 5);
  if (node >= N) return;
  int lane = (int)(t & 31);
  int o = off[node], c = cnt[node];
  float4 acc = make_float4(0.f, 0.f, 0.f, 0.f);
  for (int j = 0; j < c; ++j) {
    int s = csr[o + j];
    if (nid) s = nid[s];
    float4 v = *(const float4*)(xsrc + (size_t)s * H_DIM + lane * 4);
    acc.x += v.x; acc.y += v.y; acc.z += v.z; acc.w += v.w;
  }
  *(float4*)(agg + (size_t)node * H_DIM + lane * 4) = acc;
}

// ---------------- weight prep: W2t[col][k], k<128 -> w_l[k][col], else w_r ----
__global__ __launch_bounds__(256) void prep_w(const float* __restrict__ wl,
                                              const float* __restrict__ wr,
                                              short* __restrict__ W2) {
  int t = blockIdx.x * 256 + threadIdx.x;  // 128*256 = 32768
  int col = t >> 8, k = t & 255;
  float v = (k < 128) ? wl[k * 128 + col] : wr[(k - 128) * 128 + col];
  W2[col * 256 + k] = f2b(v);
}

// ---------------- fused SAGE linear: out = act( (agg/cnt)@w_l + x@w_r + b ) --
__global__ __launch_bounds__(256) void sage_gemm(const float* __restrict__ agg,
                                                 const int* __restrict__ cnt,
                                                 const float* __restrict__ x,
                                                 const int* __restrict__ nid,
                                                 const short* __restrict__ W2,
                                                 const float* __restrict__ bias,
                                                 float* __restrict__ out,
                                                 int N, int relu) {
  __shared__ short wlds[128 * 256];  // 64 KiB
  const int tid = threadIdx.x;
  for (int c = tid; c < 4096; c += 256) {
    int col = c >> 5, g = c & 31;
    uint4 v = *(const uint4*)(W2 + col * 256 + g * 8);
    *(uint4*)(&wlds[col * 256 + ((g ^ (col & 15)) * 8)]) = v;
  }
  __syncthreads();

  const int lane = tid & 63;
  const int wave = tid >> 6;
  const int q = lane >> 4;
  const int n16 = lane & 15;
  const int rowbase = blockIdx.x * 128 + wave * 32;

  const float* aptr[2];
  const float* xptr[2];
  float invc[2];
  for (int g = 0; g < 2; ++g) {
    int row = rowbase + g * 16 + n16;
    int rr = row < N ? row : 0;
    aptr[g] = agg + (size_t)rr * H_DIM + q * 8;
    int xr = nid ? nid[rr] : rr;
    xptr[g] = x + (size_t)xr * H_DIM + q * 8;
    int c0 = cnt[rr];
    invc[g] = 1.0f / (float)(c0 > 0 ? c0 : 1);
  }

  f32x4 acc[2][8] = {};

  for (int kt = 0; kt < 8; ++kt) {
    const int k0 = kt * 32;
    bh8 afrag[2];
    for (int g = 0; g < 2; ++g) {
      const float* p = (kt < 4) ? (aptr[g] + k0) : (xptr[g] + (k0 - 128));
      float4 v0 = *(const float4*)(p);
      float4 v1 = *(const float4*)(p + 4);
      float s = (kt < 4) ? invc[g] : 1.0f;
      bh8 a;
      a[0] = f2b(v0.x * s); a[1] = f2b(v0.y * s);
      a[2] = f2b(v0.z * s); a[3] = f2b(v0.w * s);
      a[4] = f2b(v1.x * s); a[5] = f2b(v1.y * s);
      a[6] = f2b(v1.z * s); a[7] = f2b(v1.w * s);
      afrag[g] = a;
    }
    const int swz = ((kt * 4 + q) ^ n16) * 8;
    for (int c = 0; c < 8; ++c) {
      bh8 b = *(const bh8*)(&wlds[(c * 16 + n16) * 256 + swz]);
      acc[0][c] = __builtin_amdgcn_mfma_f32_16x16x32_bf16(afrag[0], b, acc[0][c], 0, 0, 0);
      acc[1][c] = __builtin_amdgcn_mfma_f32_16x16x32_bf16(afrag[1], b, acc[1][c], 0, 0, 0);
    }
  }

  float bcol[8];
  for (int c = 0; c < 8; ++c) bcol[c] = bias[c * 16 + n16];

  for (int g = 0; g < 2; ++g) {
    for (int r = 0; r < 4; ++r) {
      int row = rowbase + g * 16 + q * 4 + r;
      if (row >= N) continue;
      float* orow = out + (size_t)row * H_DIM;
      for (int c = 0; c < 8; ++c) {
        float v = acc[g][c][r] + bcol[c];
        if (relu) v = v > 0.0f ? v : 0.0f;
        orow[c * 16 + n16] = v;
      }
    }
  }
}

// ---------------- final edge dot product ----------------
__global__ __launch_bounds__(256) void final_dot(const int* __restrict__ lbl,
                                                 const float* __restrict__ u2,
                                                 const float* __restrict__ i2,
                                                 float* __restrict__ out) {
  long t = (long)blockIdx.x * 256 + threadIdx.x;
  int e = (int)(t >> 5);
  if (e >= EL_N) return;
  int lane = (int)(t & 31);
  int lu = lbl[e];
  int li = lbl[EL_N + e];
  float4 a = *(const float4*)(u2 + (size_t)lu * H_DIM + lane * 4);
  float4 b = *(const float4*)(i2 + (size_t)li * H_DIM + lane * 4);
  float p = a.x * b.x + a.y * b.y + a.z * b.z + a.w * b.w;
  for (int off = 16; off > 0; off >>= 1) p += __shfl_down(p, off, 32);
  if (lane == 0) out[e] = p;
}

extern "C" void kernel_launch(void* const* d_in, const int* in_sizes, int n_in,
                              void* d_out, int out_size, void* d_ws, size_t ws_size,
                              hipStream_t stream) {
  const float* user_emb = (const float*)d_in[0];
  const float* item_emb = (const float*)d_in[1];
  const float* w1_ui_l = (const float*)d_in[2];
  const float* w1_ui_r = (const float*)d_in[3];
  const float* w1_iu_l = (const float*)d_in[4];
  const float* w1_iu_r = (const float*)d_in[5];
  const float* w2_ui_l = (const float*)d_in[6];
  const float* w2_ui_r = (const float*)d_in[7];
  const float* w2_iu_l = (const float*)d_in[8];
  const float* w2_iu_r = (const float*)d_in[9];
  const float* b1_ui = (const float*)d_in[10];
  const float* b1_iu = (const float*)d_in[11];
  const float* b2_ui = (const float*)d_in[12];
  const float* b2_iu = (const float*)d_in[13];
  const int* unid = (const int*)d_in[14];
  const int* inid = (const int*)d_in[15];
  const int* e_ui = (const int*)d_in[16];  // row0 users, row1 items
  const int* e_iu = (const int*)d_in[17];  // row0 items, row1 users
  const int* elbl = (const int*)d_in[18];  // row0 users, row1 items
  float* out = (float*)d_out;

  char* ws = (char*)d_ws;
  size_t o = 0;
  auto alloc = [&](size_t bytes) {
    char* p = ws + o;
    o = (o + bytes + 255) & ~(size_t)255;
    return p;
  };
  int* cnt_u = (int*)alloc((size_t)U_N * 4);
  int* cnt_i = (int*)alloc((size_t)I_N * 4);
  size_t zero_end = o;  // only cnt arrays need zeroing
  int* off_u = (int*)alloc((size_t)(U_N + 1) * 4);
  int* off_i = (int*)alloc((size_t)(I_N + 1) * 4);
  int* cur_u = (int*)alloc((size_t)U_N * 4);
  int* cur_i = (int*)alloc((size_t)I_N * 4);
  int* csr_u = (int*)alloc((size_t)E_N * 4);  // item srcs grouped by user dst
  int* csr_i = (int*)alloc((size_t)E_N * 4);  // user srcs grouped by item dst
  float* agg_u = (float*)alloc((size_t)U_N * H_DIM * 4);
  float* agg_i = (float*)alloc((size_t)I_N * H_DIM * 4);
  float* h1_u = (float*)alloc((size_t)U_N * H_DIM * 4);
  float* h1_i = (float*)alloc((size_t)I_N * H_DIM * 4);
  float* h2_u = (float*)alloc((size_t)U_N * H_DIM * 4);
  float* h2_i = (float*)alloc((size_t)I_N * H_DIM * 4);
  short* W2_1u = (short*)alloc(128 * 256 * 2);
  short* W2_1i = (short*)alloc(128 * 256 * 2);
  short* W2_2u = (short*)alloc(128 * 256 * 2);
  short* W2_2i = (short*)alloc(128 * 256 * 2);
  if (o > ws_size) {
    fprintf(stderr, "kernel_launch: ws too small, need %zu have %zu\n", o, ws_size);
    return;
  }

  hipMemsetAsync(d_ws, 0, zero_end, stream);
  count_deg<<<(E_N + 255) / 256, 256, 0, stream>>>(e_ui, cnt_u, cnt_i);
  prep_w<<<128, 256, 0, stream>>>(w1_iu_l, w1_iu_r, W2_1u);
  prep_w<<<128, 256, 0, stream>>>(w1_ui_l, w1_ui_r, W2_1i);
  prep_w<<<128, 256, 0, stream>>>(w2_iu_l, w2_iu_r, W2_2u);
  prep_w<<<128, 256, 0, stream>>>(w2_ui_l, w2_ui_r, W2_2i);

  scan_off<<<1, 1024, 0, stream>>>(cnt_u, off_u, cur_u, U_N);
  scan_off<<<1, 1024, 0, stream>>>(cnt_i, off_i, cur_i, I_N);
  // csr_u: dst=users (e_ui row0), src=items (e_ui row1)
  fill_csr<<<(E_N + 255) / 256, 256, 0, stream>>>(e_ui, e_ui + E_N, cur_u, csr_u);
  // csr_i: dst=items (e_ui row1), src=users (e_ui row0)
  fill_csr<<<(E_N + 255) / 256, 256, 0, stream>>>(e_ui + E_N, e_ui, cur_i, csr_i);

  const int gu_blocks = (U_N * 32 + 255) / 256;
  const int gi_blocks = (I_N * 32 + 255) / 256;
  // layer 1 aggregation: users <- items, items <- users
  gather_sum<<<gu_blocks, 256, 0, stream>>>(off_u, cnt_u, csr_u, inid, item_emb, agg_u, U_N);
  gather_sum<<<gi_blocks, 256, 0, stream>>>(off_i, cnt_i, csr_i, unid, user_emb, agg_i, I_N);

  sage_gemm<<<(U_N + 127) / 128, 256, 0, stream>>>(agg_u, cnt_u, user_emb, unid,
                                                   W2_1u, b1_iu, h1_u, U_N, 1);
  sage_gemm<<<(I_N + 127) / 128, 256, 0, stream>>>(agg_i, cnt_i, item_emb, inid,
                                                   W2_1i, b1_ui, h1_i, I_N, 1);

  // layer 2 aggregation (reuse CSR)
  gather_sum<<<gu_blocks, 256, 0, stream>>>(off_u, cnt_u, csr_u, nullptr, h1_i, agg_u, U_N);
  gather_sum<<<gi_blocks, 256, 0, stream>>>(off_i, cnt_i, csr_i, nullptr, h1_u, agg_i, I_N);

  sage_gemm<<<(U_N + 127) / 128, 256, 0, stream>>>(agg_u, cnt_u, h1_u, nullptr,
                                                   W2_2u, b2_iu, h2_u, U_N, 0);
  sage_gemm<<<(I_N + 127) / 128, 256, 0, stream>>>(agg_i, cnt_i, h1_i, nullptr,
                                                   W2_2i, b2_ui, h2_i, I_N, 0);

  final_dot<<<(EL_N * 32 + 255) / 256, 256, 0, stream>>>(elbl, h2_u, h2_i, out);
}

// Round 3
// 645.934 us; speedup vs baseline: 6.8089x; 1.4829x over previous
//
#include <hip/hip_runtime.h>
#include <hip/hip_bf16.h>
#include <cstdio>

#define U_N 100000
#define I_N 50000
#define H_DIM 128
#define E_N 600000
#define EL_N 200000

typedef __attribute__((ext_vector_type(8))) short bh8;
typedef __attribute__((ext_vector_type(4))) float f32x4;

// fp32 -> bf16 (RNE), self-contained
__device__ inline short f2b(float f) {
  unsigned u = __builtin_bit_cast(unsigned, f);
  u += 0x7fffu + ((u >> 16) & 1u);
  return (short)(u >> 16);
}

// ---------------- degree count (shared by both layers) ----------------
__global__ __launch_bounds__(256) void count_deg(const int* __restrict__ eui,
                                                 int* __restrict__ cu,
                                                 int* __restrict__ ci) {
  int t = blockIdx.x * 256 + threadIdx.x;
  if (t >= E_N) return;
  atomicAdd(&cu[eui[t]], 1);          // row0: users
  atomicAdd(&ci[eui[E_N + t]], 1);    // row1: items
}

// ---------------- hierarchical exclusive scan --------------------------------
// phase 1: per-block (1024-elem tile) sums
__global__ __launch_bounds__(256) void scan_p1(const int* __restrict__ cnt,
                                               int* __restrict__ bsum, int n) {
  const int t = threadIdx.x;
  const int base = blockIdx.x * 1024 + t * 4;
  int s = 0;
  for (int j = 0; j < 4; ++j) {
    int i = base + j;
    if (i < n) s += cnt[i];
  }
  for (int off = 32; off > 0; off >>= 1) s += __shfl_down(s, off, 64);
  __shared__ int wsum[4];
  if ((t & 63) == 0) wsum[t >> 6] = s;
  __syncthreads();
  if (t == 0) bsum[blockIdx.x] = wsum[0] + wsum[1] + wsum[2] + wsum[3];
}

// phase 2: exclusive-scan the block sums in place (nb <= 256)
__global__ __launch_bounds__(256) void scan_p2(int* __restrict__ bsum, int nb) {
  __shared__ int sm[256];
  const int t = threadIdx.x;
  int v = (t < nb) ? bsum[t] : 0;
  sm[t] = v;
  __syncthreads();
  for (int d = 1; d < 256; d <<= 1) {
    int x = (t >= d) ? sm[t - d] : 0;
    __syncthreads();
    sm[t] += x;
    __syncthreads();
  }
  if (t < nb) bsum[t] = sm[t] - v;  // exclusive
}

// phase 3: local exclusive scan + block base -> off, cur
__global__ __launch_bounds__(256) void scan_p3(const int* __restrict__ cnt,
                                               const int* __restrict__ bsum,
                                               int* __restrict__ off,
                                               int* __restrict__ cur, int n) {
  const int t = threadIdx.x;
  const int lane = t & 63, wv = t >> 6;
  const int base = blockIdx.x * 1024 + t * 4;
  int vals[4];
  int s = 0;
  for (int j = 0; j < 4; ++j) {
    int i = base + j;
    vals[j] = (i < n) ? cnt[i] : 0;
    s += vals[j];
  }
  int inc = s;
  for (int d = 1; d < 64; d <<= 1) {
    int x = __shfl_up(inc, d, 64);
    if (lane >= d) inc += x;
  }
  __shared__ int wsum[4];
  if (lane == 63) wsum[wv] = inc;
  __syncthreads();
  int wbase = 0;
  for (int w = 0; w < wv; ++w) wbase += wsum[w];
  int excl = wbase + (inc - s) + bsum[blockIdx.x];
  for (int j = 0; j < 4; ++j) {
    int i = base + j;
    if (i < n) { off[i] = excl; cur[i] = excl; }
    excl += vals[j];
  }
}

// ---------------- CSR fill: csr[pos] = src, grouped by dst ------------------
__global__ __launch_bounds__(256) void fill_csr(const int* __restrict__ dst,
                                                const int* __restrict__ src,
                                                int* __restrict__ cur,
                                                int* __restrict__ csr) {
  int t = blockIdx.x * 256 + threadIdx.x;
  if (t >= E_N) return;
  int pos = atomicAdd(&cur[dst[t]], 1);
  csr[pos] = src[t];
}

// ---------------- gather-aggregate: agg[d] = sum_{j in N(d)} x[j] -----------
// half-wave (32 lanes) per destination node; 16B/lane contiguous reads
__global__ __launch_bounds__(256) void gather_sum(const int* __restrict__ off,
                                                  const int* __restrict__ cnt,
                                                  const int* __restrict__ csr,
                                                  const int* __restrict__ nid,
                                                  const float* __restrict__ xsrc,
                                                  float* __restrict__ agg, int N) {
  long t = (long)blockIdx.x * 256 + threadIdx.x;
  int node = (int)(t >> 5);
  if (node >= N) return;
  int lane = (int)(t & 31);
  int o = off[node], c = cnt[node];
  float4 acc = make_float4(0.f, 0.f, 0.f, 0.f);
  for (int j = 0; j < c; ++j) {
    int s = csr[o + j];
    if (nid) s = nid[s];
    float4 v = *(const float4*)(xsrc + (size_t)s * H_DIM + lane * 4);
    acc.x += v.x; acc.y += v.y; acc.z += v.z; acc.w += v.w;
  }
  *(float4*)(agg + (size_t)node * H_DIM + lane * 4) = acc;
}

// ---------------- weight prep: W2t[col][k], k<128 -> w_l[k][col], else w_r ----
__global__ __launch_bounds__(256) void prep_w(const float* __restrict__ wl,
                                              const float* __restrict__ wr,
                                              short* __restrict__ W2) {
  int t = blockIdx.x * 256 + threadIdx.x;  // 128*256 = 32768
  int col = t >> 8, k = t & 255;
  float v = (k < 128) ? wl[k * 128 + col] : wr[(k - 128) * 128 + col];
  W2[col * 256 + k] = f2b(v);
}

// ---------------- fused SAGE linear: out = act( (agg/cnt)@w_l + x@w_r + b ) --
__global__ __launch_bounds__(256) void sage_gemm(const float* __restrict__ agg,
                                                 const int* __restrict__ cnt,
                                                 const float* __restrict__ x,
                                                 const int* __restrict__ nid,
                                                 const short* __restrict__ W2,
                                                 const float* __restrict__ bias,
                                                 float* __restrict__ out,
                                                 int N, int relu) {
  __shared__ short wlds[128 * 256];  // 64 KiB
  const int tid = threadIdx.x;
  for (int c = tid; c < 4096; c += 256) {
    int col = c >> 5, g = c & 31;
    uint4 v = *(const uint4*)(W2 + col * 256 + g * 8);
    *(uint4*)(&wlds[col * 256 + ((g ^ (col & 15)) * 8)]) = v;
  }
  __syncthreads();

  const int lane = tid & 63;
  const int wave = tid >> 6;
  const int q = lane >> 4;
  const int n16 = lane & 15;
  const int rowbase = blockIdx.x * 128 + wave * 32;

  const float* aptr[2];
  const float* xptr[2];
  float invc[2];
  for (int g = 0; g < 2; ++g) {
    int row = rowbase + g * 16 + n16;
    int rr = row < N ? row : 0;
    aptr[g] = agg + (size_t)rr * H_DIM + q * 8;
    int xr = nid ? nid[rr] : rr;
    xptr[g] = x + (size_t)xr * H_DIM + q * 8;
    int c0 = cnt[rr];
    invc[g] = 1.0f / (float)(c0 > 0 ? c0 : 1);
  }

  f32x4 acc[2][8] = {};

  for (int kt = 0; kt < 8; ++kt) {
    const int k0 = kt * 32;
    bh8 afrag[2];
    for (int g = 0; g < 2; ++g) {
      const float* p = (kt < 4) ? (aptr[g] + k0) : (xptr[g] + (k0 - 128));
      float4 v0 = *(const float4*)(p);
      float4 v1 = *(const float4*)(p + 4);
      float s = (kt < 4) ? invc[g] : 1.0f;
      bh8 a;
      a[0] = f2b(v0.x * s); a[1] = f2b(v0.y * s);
      a[2] = f2b(v0.z * s); a[3] = f2b(v0.w * s);
      a[4] = f2b(v1.x * s); a[5] = f2b(v1.y * s);
      a[6] = f2b(v1.z * s); a[7] = f2b(v1.w * s);
      afrag[g] = a;
    }
    const int swz = ((kt * 4 + q) ^ n16) * 8;
    for (int c = 0; c < 8; ++c) {
      bh8 b = *(const bh8*)(&wlds[(c * 16 + n16) * 256 + swz]);
      acc[0][c] = __builtin_amdgcn_mfma_f32_16x16x32_bf16(afrag[0], b, acc[0][c], 0, 0, 0);
      acc[1][c] = __builtin_amdgcn_mfma_f32_16x16x32_bf16(afrag[1], b, acc[1][c], 0, 0, 0);
    }
  }

  float bcol[8];
  for (int c = 0; c < 8; ++c) bcol[c] = bias[c * 16 + n16];

  for (int g = 0; g < 2; ++g) {
    for (int r = 0; r < 4; ++r) {
      int row = rowbase + g * 16 + q * 4 + r;
      if (row >= N) continue;
      float* orow = out + (size_t)row * H_DIM;
      for (int c = 0; c < 8; ++c) {
        float v = acc[g][c][r] + bcol[c];
        if (relu) v = v > 0.0f ? v : 0.0f;
        orow[c * 16 + n16] = v;
      }
    }
  }
}

// ---------------- final edge dot product ----------------
__global__ __launch_bounds__(256) void final_dot(const int* __restrict__ lbl,
                                                 const float* __restrict__ u2,
                                                 const float* __restrict__ i2,
                                                 float* __restrict__ out) {
  long t = (long)blockIdx.x * 256 + threadIdx.x;
  int e = (int)(t >> 5);
  if (e >= EL_N) return;
  int lane = (int)(t & 31);
  int lu = lbl[e];
  int li = lbl[EL_N + e];
  float4 a = *(const float4*)(u2 + (size_t)lu * H_DIM + lane * 4);
  float4 b = *(const float4*)(i2 + (size_t)li * H_DIM + lane * 4);
  float p = a.x * b.x + a.y * b.y + a.z * b.z + a.w * b.w;
  for (int off = 16; off > 0; off >>= 1) p += __shfl_down(p, off, 32);
  if (lane == 0) out[e] = p;
}

extern "C" void kernel_launch(void* const* d_in, const int* in_sizes, int n_in,
                              void* d_out, int out_size, void* d_ws, size_t ws_size,
                              hipStream_t stream) {
  const float* user_emb = (const float*)d_in[0];
  const float* item_emb = (const float*)d_in[1];
  const float* w1_ui_l = (const float*)d_in[2];
  const float* w1_ui_r = (const float*)d_in[3];
  const float* w1_iu_l = (const float*)d_in[4];
  const float* w1_iu_r = (const float*)d_in[5];
  const float* w2_ui_l = (const float*)d_in[6];
  const float* w2_ui_r = (const float*)d_in[7];
  const float* w2_iu_l = (const float*)d_in[8];
  const float* w2_iu_r = (const float*)d_in[9];
  const float* b1_ui = (const float*)d_in[10];
  const float* b1_iu = (const float*)d_in[11];
  const float* b2_ui = (const float*)d_in[12];
  const float* b2_iu = (const float*)d_in[13];
  const int* unid = (const int*)d_in[14];
  const int* inid = (const int*)d_in[15];
  const int* e_ui = (const int*)d_in[16];  // row0 users, row1 items
  const int* e_iu = (const int*)d_in[17];  // row0 items, row1 users
  const int* elbl = (const int*)d_in[18];  // row0 users, row1 items
  float* out = (float*)d_out;

  char* ws = (char*)d_ws;
  size_t o = 0;
  auto alloc = [&](size_t bytes) {
    char* p = ws + o;
    o = (o + bytes + 255) & ~(size_t)255;
    return p;
  };
  int* cnt_u = (int*)alloc((size_t)U_N * 4);
  int* cnt_i = (int*)alloc((size_t)I_N * 4);
  size_t zero_end = o;  // only cnt arrays need zeroing
  int* off_u = (int*)alloc((size_t)(U_N + 1) * 4);
  int* off_i = (int*)alloc((size_t)(I_N + 1) * 4);
  int* cur_u = (int*)alloc((size_t)U_N * 4);
  int* cur_i = (int*)alloc((size_t)I_N * 4);
  int* csr_u = (int*)alloc((size_t)E_N * 4);  // item srcs grouped by user dst
  int* csr_i = (int*)alloc((size_t)E_N * 4);  // user srcs grouped by item dst
  int* bsum_u = (int*)alloc(256 * 4);
  int* bsum_i = (int*)alloc(256 * 4);
  float* agg_u = (float*)alloc((size_t)U_N * H_DIM * 4);
  float* agg_i = (float*)alloc((size_t)I_N * H_DIM * 4);
  float* h1_u = (float*)alloc((size_t)U_N * H_DIM * 4);
  float* h1_i = (float*)alloc((size_t)I_N * H_DIM * 4);
  float* h2_u = (float*)alloc((size_t)U_N * H_DIM * 4);
  float* h2_i = (float*)alloc((size_t)I_N * H_DIM * 4);
  short* W2_1u = (short*)alloc(128 * 256 * 2);
  short* W2_1i = (short*)alloc(128 * 256 * 2);
  short* W2_2u = (short*)alloc(128 * 256 * 2);
  short* W2_2i = (short*)alloc(128 * 256 * 2);
  if (o > ws_size) {
    fprintf(stderr, "kernel_launch: ws too small, need %zu have %zu\n", o, ws_size);
    return;
  }

  const int nb_u = (U_N + 1023) / 1024;  // 98
  const int nb_i = (I_N + 1023) / 1024;  // 49

  hipMemsetAsync(d_ws, 0, zero_end, stream);
  count_deg<<<(E_N + 255) / 256, 256, 0, stream>>>(e_ui, cnt_u, cnt_i);
  prep_w<<<128, 256, 0, stream>>>(w1_iu_l, w1_iu_r, W2_1u);
  prep_w<<<128, 256, 0, stream>>>(w1_ui_l, w1_ui_r, W2_1i);
  prep_w<<<128, 256, 0, stream>>>(w2_iu_l, w2_iu_r, W2_2u);
  prep_w<<<128, 256, 0, stream>>>(w2_ui_l, w2_ui_r, W2_2i);

  scan_p1<<<nb_u, 256, 0, stream>>>(cnt_u, bsum_u, U_N);
  scan_p1<<<nb_i, 256, 0, stream>>>(cnt_i, bsum_i, I_N);
  scan_p2<<<1, 256, 0, stream>>>(bsum_u, nb_u);
  scan_p2<<<1, 256, 0, stream>>>(bsum_i, nb_i);
  scan_p3<<<nb_u, 256, 0, stream>>>(cnt_u, bsum_u, off_u, cur_u, U_N);
  scan_p3<<<nb_i, 256, 0, stream>>>(cnt_i, bsum_i, off_i, cur_i, I_N);

  // csr_u: dst=users (e_ui row0), src=items (e_ui row1)
  fill_csr<<<(E_N + 255) / 256, 256, 0, stream>>>(e_ui, e_ui + E_N, cur_u, csr_u);
  // csr_i: dst=items (e_ui row1), src=users (e_ui row0)
  fill_csr<<<(E_N + 255) / 256, 256, 0, stream>>>(e_ui + E_N, e_ui, cur_i, csr_i);

  const int gu_blocks = (U_N * 32 + 255) / 256;
  const int gi_blocks = (I_N * 32 + 255) / 256;
  // layer 1 aggregation: users <- items, items <- users
  gather_sum<<<gu_blocks, 256, 0, stream>>>(off_u, cnt_u, csr_u, inid, item_emb, agg_u, U_N);
  gather_sum<<<gi_blocks, 256, 0, stream>>>(off_i, cnt_i, csr_i, unid, user_emb, agg_i, I_N);

  sage_gemm<<<(U_N + 127) / 128, 256, 0, stream>>>(agg_u, cnt_u, user_emb, unid,
                                                   W2_1u, b1_iu, h1_u, U_N, 1);
  sage_gemm<<<(I_N + 127) / 128, 256, 0, stream>>>(agg_i, cnt_i, item_emb, inid,
                                                   W2_1i, b1_ui, h1_i, I_N, 1);

  // layer 2 aggregation (reuse CSR)
  gather_sum<<<gu_blocks, 256, 0, stream>>>(off_u, cnt_u, csr_u, nullptr, h1_i, agg_u, U_N);
  gather_sum<<<gi_blocks, 256, 0, stream>>>(off_i, cnt_i, csr_i, nullptr, h1_u, agg_i, I_N);

  sage_gemm<<<(U_N + 127) / 128, 256, 0, stream>>>(agg_u, cnt_u, h1_u, nullptr,
                                                   W2_2u, b2_iu, h2_u, U_N, 0);
  sage_gemm<<<(I_N + 127) / 128, 256, 0, stream>>>(agg_i, cnt_i, h1_i, nullptr,
                                                   W2_2i, b2_ui, h2_i, I_N, 0);

  final_dot<<<(EL_N * 32 + 255) / 256, 256, 0, stream>>>(elbl, h2_u, h2_i, out);
}

// Round 4
// 549.030 us; speedup vs baseline: 8.0106x; 1.1765x over previous
//
#include <hip/hip_runtime.h>
#include <hip/hip_bf16.h>
#include <cstdio>

#define U_N 100000
#define I_N 50000
#define H_DIM 128
#define E_N 600000
#define EL_N 200000

typedef __attribute__((ext_vector_type(8))) short bh8;
typedef __attribute__((ext_vector_type(4))) float f32x4;
typedef __attribute__((ext_vector_type(4))) unsigned short u16x4;
typedef __attribute__((ext_vector_type(8))) unsigned short u16x8;

// fp32 -> bf16 (RNE)
__device__ inline unsigned short f2b(float f) {
  unsigned u = __builtin_bit_cast(unsigned, f);
  u += 0x7fffu + ((u >> 16) & 1u);
  return (unsigned short)(u >> 16);
}
// bf16 bits -> fp32
__device__ inline float b2f(unsigned short h) {
  unsigned u = ((unsigned)h) << 16;
  return __builtin_bit_cast(float, u);
}

// ---------------- degree count (shared by both layers) ----------------
__global__ __launch_bounds__(256) void count_deg(const int* __restrict__ eui,
                                                 int* __restrict__ cu,
                                                 int* __restrict__ ci) {
  int t = blockIdx.x * 256 + threadIdx.x;
  if (t >= E_N) return;
  atomicAdd(&cu[eui[t]], 1);          // row0: users
  atomicAdd(&ci[eui[E_N + t]], 1);    // row1: items
}

// ---------------- embedding convert (applies node_id gather) ----------------
__global__ __launch_bounds__(256) void cvt_emb(const float* __restrict__ x,
                                               const int* __restrict__ nid,
                                               unsigned short* __restrict__ xb,
                                               int N) {
  int t = blockIdx.x * 256 + threadIdx.x;  // N*16 threads, 8 elems each
  if (t >= N * 16) return;
  int row = t >> 4, seg = t & 15;
  int r = nid ? nid[row] : row;
  const float* p = x + (size_t)r * H_DIM + seg * 8;
  float4 a = ((const float4*)p)[0];
  float4 b = ((const float4*)p)[1];
  u16x8 v;
  v[0] = f2b(a.x); v[1] = f2b(a.y); v[2] = f2b(a.z); v[3] = f2b(a.w);
  v[4] = f2b(b.x); v[5] = f2b(b.y); v[6] = f2b(b.z); v[7] = f2b(b.w);
  *(u16x8*)(xb + (size_t)row * H_DIM + seg * 8) = v;
}

// ---------------- hierarchical exclusive scan --------------------------------
__global__ __launch_bounds__(256) void scan_p1(const int* __restrict__ cnt,
                                               int* __restrict__ bsum, int n) {
  const int t = threadIdx.x;
  const int base = blockIdx.x * 1024 + t * 4;
  int s = 0;
  for (int j = 0; j < 4; ++j) {
    int i = base + j;
    if (i < n) s += cnt[i];
  }
  for (int off = 32; off > 0; off >>= 1) s += __shfl_down(s, off, 64);
  __shared__ int wsum[4];
  if ((t & 63) == 0) wsum[t >> 6] = s;
  __syncthreads();
  if (t == 0) bsum[blockIdx.x] = wsum[0] + wsum[1] + wsum[2] + wsum[3];
}

__global__ __launch_bounds__(256) void scan_p2(int* __restrict__ bsum, int nb) {
  __shared__ int sm[256];
  const int t = threadIdx.x;
  int v = (t < nb) ? bsum[t] : 0;
  sm[t] = v;
  __syncthreads();
  for (int d = 1; d < 256; d <<= 1) {
    int x = (t >= d) ? sm[t - d] : 0;
    __syncthreads();
    sm[t] += x;
    __syncthreads();
  }
  if (t < nb) bsum[t] = sm[t] - v;  // exclusive
}

__global__ __launch_bounds__(256) void scan_p3(const int* __restrict__ cnt,
                                               const int* __restrict__ bsum,
                                               int* __restrict__ off,
                                               int* __restrict__ cur, int n) {
  const int t = threadIdx.x;
  const int lane = t & 63, wv = t >> 6;
  const int base = blockIdx.x * 1024 + t * 4;
  int vals[4];
  int s = 0;
  for (int j = 0; j < 4; ++j) {
    int i = base + j;
    vals[j] = (i < n) ? cnt[i] : 0;
    s += vals[j];
  }
  int inc = s;
  for (int d = 1; d < 64; d <<= 1) {
    int x = __shfl_up(inc, d, 64);
    if (lane >= d) inc += x;
  }
  __shared__ int wsum[4];
  if (lane == 63) wsum[wv] = inc;
  __syncthreads();
  int wbase = 0;
  for (int w = 0; w < wv; ++w) wbase += wsum[w];
  int excl = wbase + (inc - s) + bsum[blockIdx.x];
  for (int j = 0; j < 4; ++j) {
    int i = base + j;
    if (i < n) { off[i] = excl; cur[i] = excl; }
    excl += vals[j];
  }
}

// ---------------- CSR fill: csr[pos] = src, grouped by dst ------------------
__global__ __launch_bounds__(256) void fill_csr(const int* __restrict__ dst,
                                                const int* __restrict__ src,
                                                int* __restrict__ cur,
                                                int* __restrict__ csr) {
  int t = blockIdx.x * 256 + threadIdx.x;
  if (t >= E_N) return;
  int pos = atomicAdd(&cur[dst[t]], 1);
  csr[pos] = src[t];
}

// ---------------- gather-mean (bf16 in, bf16 mean out) ----------------------
// half-wave (32 lanes) per destination node; 8B/lane contiguous reads.
// CSR indices prefetched 32-at-a-time, broadcast via shfl.
__global__ __launch_bounds__(256) void gather_mean(const int* __restrict__ off,
                                                   const int* __restrict__ cnt,
                                                   const int* __restrict__ csr,
                                                   const unsigned short* __restrict__ xb,
                                                   unsigned short* __restrict__ aggb,
                                                   int N) {
  long t = (long)blockIdx.x * 256 + threadIdx.x;
  int node = (int)(t >> 5);
  if (node >= N) return;
  int lane = (int)(t & 31);
  int o = off[node], c = cnt[node];
  float4 acc = make_float4(0.f, 0.f, 0.f, 0.f);
  for (int j0 = 0; j0 < c; j0 += 32) {
    int nj = c - j0;
    if (nj > 32) nj = 32;
    int sidx = (lane < nj) ? csr[o + j0 + lane] : 0;
    for (int j = 0; j < nj; ++j) {
      int s = __shfl(sidx, j, 32);
      u16x4 v = *(const u16x4*)(xb + (size_t)s * H_DIM + lane * 4);
      acc.x += b2f(v[0]); acc.y += b2f(v[1]);
      acc.z += b2f(v[2]); acc.w += b2f(v[3]);
    }
  }
  float inv = 1.0f / (float)(c > 0 ? c : 1);
  u16x4 r;
  r[0] = f2b(acc.x * inv); r[1] = f2b(acc.y * inv);
  r[2] = f2b(acc.z * inv); r[3] = f2b(acc.w * inv);
  *(u16x4*)(aggb + (size_t)node * H_DIM + lane * 4) = r;
}

// ---------------- weight prep: W2t[col][k], k<128 -> w_l[k][col], else w_r ----
__global__ __launch_bounds__(256) void prep_w(const float* __restrict__ wl,
                                              const float* __restrict__ wr,
                                              short* __restrict__ W2) {
  int t = blockIdx.x * 256 + threadIdx.x;  // 128*256 = 32768
  int col = t >> 8, k = t & 255;
  float v = (k < 128) ? wl[k * 128 + col] : wr[(k - 128) * 128 + col];
  W2[col * 256 + k] = (short)f2b(v);
}

// ---------------- fused SAGE linear: out = act( mean@w_l + x@w_r + b ) -------
// A-side is pure bf16 loads: aggb (pre-divided mean) for k<128, xb for k>=128.
// out: bf16 (h1) if outb != null, else fp32 (h2) to outf.
__global__ __launch_bounds__(256) void sage_gemm(const unsigned short* __restrict__ aggb,
                                                 const unsigned short* __restrict__ xb,
                                                 const short* __restrict__ W2,
                                                 const float* __restrict__ bias,
                                                 unsigned short* __restrict__ outb,
                                                 float* __restrict__ outf,
                                                 int N, int relu) {
  __shared__ short wlds[128 * 256];  // 64 KiB
  const int tid = threadIdx.x;
  for (int c = tid; c < 4096; c += 256) {
    int col = c >> 5, g = c & 31;
    uint4 v = *(const uint4*)(W2 + col * 256 + g * 8);
    *(uint4*)(&wlds[col * 256 + ((g ^ (col & 15)) * 8)]) = v;
  }
  __syncthreads();

  const int lane = tid & 63;
  const int wave = tid >> 6;
  const int q = lane >> 4;
  const int n16 = lane & 15;
  const int rowbase = blockIdx.x * 128 + wave * 32;

  const unsigned short* aptr[2];
  const unsigned short* xptr[2];
  for (int g = 0; g < 2; ++g) {
    int row = rowbase + g * 16 + n16;
    int rr = row < N ? row : 0;
    aptr[g] = aggb + (size_t)rr * H_DIM + q * 8;
    xptr[g] = xb + (size_t)rr * H_DIM + q * 8;
  }

  f32x4 acc[2][8] = {};

  for (int kt = 0; kt < 8; ++kt) {
    const int k0 = kt * 32;
    bh8 afrag[2];
    for (int g = 0; g < 2; ++g) {
      const unsigned short* p = (kt < 4) ? (aptr[g] + k0) : (xptr[g] + (k0 - 128));
      afrag[g] = *(const bh8*)(p);
    }
    const int swz = ((kt * 4 + q) ^ n16) * 8;
    for (int c = 0; c < 8; ++c) {
      bh8 b = *(const bh8*)(&wlds[(c * 16 + n16) * 256 + swz]);
      acc[0][c] = __builtin_amdgcn_mfma_f32_16x16x32_bf16(afrag[0], b, acc[0][c], 0, 0, 0);
      acc[1][c] = __builtin_amdgcn_mfma_f32_16x16x32_bf16(afrag[1], b, acc[1][c], 0, 0, 0);
    }
  }

  float bcol[8];
  for (int c = 0; c < 8; ++c) bcol[c] = bias[c * 16 + n16];

  for (int g = 0; g < 2; ++g) {
    for (int r = 0; r < 4; ++r) {
      int row = rowbase + g * 16 + q * 4 + r;
      if (row >= N) continue;
      for (int c = 0; c < 8; ++c) {
        float v = acc[g][c][r] + bcol[c];
        if (relu) v = v > 0.0f ? v : 0.0f;
        if (outb) outb[(size_t)row * H_DIM + c * 16 + n16] = f2b(v);
        else      outf[(size_t)row * H_DIM + c * 16 + n16] = v;
      }
    }
  }
}

// ---------------- final edge dot product (h2 fp32) ----------------
__global__ __launch_bounds__(256) void final_dot(const int* __restrict__ lbl,
                                                 const float* __restrict__ u2,
                                                 const float* __restrict__ i2,
                                                 float* __restrict__ out) {
  long t = (long)blockIdx.x * 256 + threadIdx.x;
  int e = (int)(t >> 5);
  if (e >= EL_N) return;
  int lane = (int)(t & 31);
  int lu = lbl[e];
  int li = lbl[EL_N + e];
  float4 a = *(const float4*)(u2 + (size_t)lu * H_DIM + lane * 4);
  float4 b = *(const float4*)(i2 + (size_t)li * H_DIM + lane * 4);
  float p = a.x * b.x + a.y * b.y + a.z * b.z + a.w * b.w;
  for (int off = 16; off > 0; off >>= 1) p += __shfl_down(p, off, 32);
  if (lane == 0) out[e] = p;
}

extern "C" void kernel_launch(void* const* d_in, const int* in_sizes, int n_in,
                              void* d_out, int out_size, void* d_ws, size_t ws_size,
                              hipStream_t stream) {
  const float* user_emb = (const float*)d_in[0];
  const float* item_emb = (const float*)d_in[1];
  const float* w1_ui_l = (const float*)d_in[2];
  const float* w1_ui_r = (const float*)d_in[3];
  const float* w1_iu_l = (const float*)d_in[4];
  const float* w1_iu_r = (const float*)d_in[5];
  const float* w2_ui_l = (const float*)d_in[6];
  const float* w2_ui_r = (const float*)d_in[7];
  const float* w2_iu_l = (const float*)d_in[8];
  const float* w2_iu_r = (const float*)d_in[9];
  const float* b1_ui = (const float*)d_in[10];
  const float* b1_iu = (const float*)d_in[11];
  const float* b2_ui = (const float*)d_in[12];
  const float* b2_iu = (const float*)d_in[13];
  const int* unid = (const int*)d_in[14];
  const int* inid = (const int*)d_in[15];
  const int* e_ui = (const int*)d_in[16];  // row0 users, row1 items
  const int* e_iu = (const int*)d_in[17];  // row0 items, row1 users
  const int* elbl = (const int*)d_in[18];  // row0 users, row1 items
  float* out = (float*)d_out;

  char* ws = (char*)d_ws;
  size_t o = 0;
  auto alloc = [&](size_t bytes) {
    char* p = ws + o;
    o = (o + bytes + 255) & ~(size_t)255;
    return p;
  };
  int* cnt_u = (int*)alloc((size_t)U_N * 4);
  int* cnt_i = (int*)alloc((size_t)I_N * 4);
  size_t zero_end = o;  // only cnt arrays need zeroing
  int* off_u = (int*)alloc((size_t)(U_N + 1) * 4);
  int* off_i = (int*)alloc((size_t)(I_N + 1) * 4);
  int* cur_u = (int*)alloc((size_t)U_N * 4);
  int* cur_i = (int*)alloc((size_t)I_N * 4);
  int* csr_u = (int*)alloc((size_t)E_N * 4);  // item srcs grouped by user dst
  int* csr_i = (int*)alloc((size_t)E_N * 4);  // user srcs grouped by item dst
  int* bsum_u = (int*)alloc(256 * 4);
  int* bsum_i = (int*)alloc(256 * 4);
  unsigned short* ue_b = (unsigned short*)alloc((size_t)U_N * H_DIM * 2);
  unsigned short* ie_b = (unsigned short*)alloc((size_t)I_N * H_DIM * 2);
  unsigned short* agg_u = (unsigned short*)alloc((size_t)U_N * H_DIM * 2);
  unsigned short* agg_i = (unsigned short*)alloc((size_t)I_N * H_DIM * 2);
  unsigned short* h1_u = (unsigned short*)alloc((size_t)U_N * H_DIM * 2);
  unsigned short* h1_i = (unsigned short*)alloc((size_t)I_N * H_DIM * 2);
  float* h2_u = (float*)alloc((size_t)U_N * H_DIM * 4);
  float* h2_i = (float*)alloc((size_t)I_N * H_DIM * 4);
  short* W2_1u = (short*)alloc(128 * 256 * 2);
  short* W2_1i = (short*)alloc(128 * 256 * 2);
  short* W2_2u = (short*)alloc(128 * 256 * 2);
  short* W2_2i = (short*)alloc(128 * 256 * 2);
  if (o > ws_size) {
    fprintf(stderr, "kernel_launch: ws too small, need %zu have %zu\n", o, ws_size);
    return;
  }

  const int nb_u = (U_N + 1023) / 1024;  // 98
  const int nb_i = (I_N + 1023) / 1024;  // 49

  hipMemsetAsync(d_ws, 0, zero_end, stream);
  count_deg<<<(E_N + 255) / 256, 256, 0, stream>>>(e_ui, cnt_u, cnt_i);
  cvt_emb<<<(U_N * 16 + 255) / 256, 256, 0, stream>>>(user_emb, unid, ue_b, U_N);
  cvt_emb<<<(I_N * 16 + 255) / 256, 256, 0, stream>>>(item_emb, inid, ie_b, I_N);
  prep_w<<<128, 256, 0, stream>>>(w1_iu_l, w1_iu_r, W2_1u);
  prep_w<<<128, 256, 0, stream>>>(w1_ui_l, w1_ui_r, W2_1i);
  prep_w<<<128, 256, 0, stream>>>(w2_iu_l, w2_iu_r, W2_2u);
  prep_w<<<128, 256, 0, stream>>>(w2_ui_l, w2_ui_r, W2_2i);

  scan_p1<<<nb_u, 256, 0, stream>>>(cnt_u, bsum_u, U_N);
  scan_p1<<<nb_i, 256, 0, stream>>>(cnt_i, bsum_i, I_N);
  scan_p2<<<1, 256, 0, stream>>>(bsum_u, nb_u);
  scan_p2<<<1, 256, 0, stream>>>(bsum_i, nb_i);
  scan_p3<<<nb_u, 256, 0, stream>>>(cnt_u, bsum_u, off_u, cur_u, U_N);
  scan_p3<<<nb_i, 256, 0, stream>>>(cnt_i, bsum_i, off_i, cur_i, I_N);

  fill_csr<<<(E_N + 255) / 256, 256, 0, stream>>>(e_ui, e_ui + E_N, cur_u, csr_u);
  fill_csr<<<(E_N + 255) / 256, 256, 0, stream>>>(e_ui + E_N, e_ui, cur_i, csr_i);

  const int gu_blocks = (U_N * 32 + 255) / 256;
  const int gi_blocks = (I_N * 32 + 255) / 256;
  // layer 1: users <- items, items <- users (bf16 mean out)
  gather_mean<<<gu_blocks, 256, 0, stream>>>(off_u, cnt_u, csr_u, ie_b, agg_u, U_N);
  gather_mean<<<gi_blocks, 256, 0, stream>>>(off_i, cnt_i, csr_i, ue_b, agg_i, I_N);

  sage_gemm<<<(U_N + 127) / 128, 256, 0, stream>>>(agg_u, ue_b, W2_1u, b1_iu,
                                                   h1_u, nullptr, U_N, 1);
  sage_gemm<<<(I_N + 127) / 128, 256, 0, stream>>>(agg_i, ie_b, W2_1i, b1_ui,
                                                   h1_i, nullptr, I_N, 1);

  // layer 2 (reuse CSR)
  gather_mean<<<gu_blocks, 256, 0, stream>>>(off_u, cnt_u, csr_u, h1_i, agg_u, U_N);
  gather_mean<<<gi_blocks, 256, 0, stream>>>(off_i, cnt_i, csr_i, h1_u, agg_i, I_N);

  sage_gemm<<<(U_N + 127) / 128, 256, 0, stream>>>(agg_u, h1_u, W2_2u, b2_iu,
                                                   nullptr, h2_u, U_N, 0);
  sage_gemm<<<(I_N + 127) / 128, 256, 0, stream>>>(agg_i, h1_i, W2_2i, b2_ui,
                                                   nullptr, h2_i, I_N, 0);

  final_dot<<<(EL_N * 32 + 255) / 256, 256, 0, stream>>>(elbl, h2_u, h2_i, out);
}

// Round 5
// 517.937 us; speedup vs baseline: 8.4915x; 1.0600x over previous
//
#include <hip/hip_runtime.h>
#include <hip/hip_bf16.h>
#include <cstdio>

#define U_N 100000
#define I_N 50000
#define H_DIM 128
#define E_N 600000
#define EL_N 200000

typedef __attribute__((ext_vector_type(8))) short bh8;
typedef __attribute__((ext_vector_type(4))) float f32x4;
typedef __attribute__((ext_vector_type(4))) unsigned short u16x4;
typedef __attribute__((ext_vector_type(8))) unsigned short u16x8;

// fp32 -> bf16 (RNE)
__device__ inline unsigned short f2b(float f) {
  unsigned u = __builtin_bit_cast(unsigned, f);
  u += 0x7fffu + ((u >> 16) & 1u);
  return (unsigned short)(u >> 16);
}
// bf16 bits -> fp32
__device__ inline float b2f(unsigned short h) {
  unsigned u = ((unsigned)h) << 16;
  return __builtin_bit_cast(float, u);
}

// ---------------- degree count, 8-way XCD-partitioned ----------------
__global__ __launch_bounds__(256) void count_deg8(const int* __restrict__ eui,
                                                  int* __restrict__ c8u,
                                                  int* __restrict__ c8i) {
  int t = blockIdx.x * 256 + threadIdx.x;
  if (t >= E_N) return;
  int p = blockIdx.x & 7;
  atomicAdd(&c8u[p * U_N + eui[t]], 1);          // row0: users
  atomicAdd(&c8i[p * I_N + eui[E_N + t]], 1);    // row1: items
}

// cnt[node] = sum_p c8[p][node]
__global__ __launch_bounds__(256) void reduce_cnt(const int* __restrict__ c8,
                                                  int* __restrict__ cnt, int N) {
  int t = blockIdx.x * 256 + threadIdx.x;
  if (t >= N) return;
  int s = 0;
  for (int p = 0; p < 8; ++p) s += c8[p * N + t];
  cnt[t] = s;
}

// cur8[p][node] = off[node] + sum_{q<p} c8[q][node]
__global__ __launch_bounds__(256) void init_cur8(const int* __restrict__ c8,
                                                 const int* __restrict__ off,
                                                 int* __restrict__ cur8, int N) {
  int t = blockIdx.x * 256 + threadIdx.x;
  if (t >= N) return;
  int base = off[t];
  for (int p = 0; p < 8; ++p) {
    cur8[p * N + t] = base;
    base += c8[p * N + t];
  }
}

// ---------------- embedding convert (applies node_id gather) ----------------
__global__ __launch_bounds__(256) void cvt_emb(const float* __restrict__ x,
                                               const int* __restrict__ nid,
                                               unsigned short* __restrict__ xb,
                                               int N) {
  int t = blockIdx.x * 256 + threadIdx.x;  // N*16 threads, 8 elems each
  if (t >= N * 16) return;
  int row = t >> 4, seg = t & 15;
  int r = nid ? nid[row] : row;
  const float* p = x + (size_t)r * H_DIM + seg * 8;
  float4 a = ((const float4*)p)[0];
  float4 b = ((const float4*)p)[1];
  u16x8 v;
  v[0] = f2b(a.x); v[1] = f2b(a.y); v[2] = f2b(a.z); v[3] = f2b(a.w);
  v[4] = f2b(b.x); v[5] = f2b(b.y); v[6] = f2b(b.z); v[7] = f2b(b.w);
  *(u16x8*)(xb + (size_t)row * H_DIM + seg * 8) = v;
}

// ---------------- hierarchical exclusive scan --------------------------------
__global__ __launch_bounds__(256) void scan_p1(const int* __restrict__ cnt,
                                               int* __restrict__ bsum, int n) {
  const int t = threadIdx.x;
  const int base = blockIdx.x * 1024 + t * 4;
  int s = 0;
  for (int j = 0; j < 4; ++j) {
    int i = base + j;
    if (i < n) s += cnt[i];
  }
  for (int off = 32; off > 0; off >>= 1) s += __shfl_down(s, off, 64);
  __shared__ int wsum[4];
  if ((t & 63) == 0) wsum[t >> 6] = s;
  __syncthreads();
  if (t == 0) bsum[blockIdx.x] = wsum[0] + wsum[1] + wsum[2] + wsum[3];
}

__global__ __launch_bounds__(256) void scan_p2(int* __restrict__ bsum, int nb) {
  __shared__ int sm[256];
  const int t = threadIdx.x;
  int v = (t < nb) ? bsum[t] : 0;
  sm[t] = v;
  __syncthreads();
  for (int d = 1; d < 256; d <<= 1) {
    int x = (t >= d) ? sm[t - d] : 0;
    __syncthreads();
    sm[t] += x;
    __syncthreads();
  }
  if (t < nb) bsum[t] = sm[t] - v;  // exclusive
}

__global__ __launch_bounds__(256) void scan_p3(const int* __restrict__ cnt,
                                               const int* __restrict__ bsum,
                                               int* __restrict__ off, int n) {
  const int t = threadIdx.x;
  const int lane = t & 63, wv = t >> 6;
  const int base = blockIdx.x * 1024 + t * 4;
  int vals[4];
  int s = 0;
  for (int j = 0; j < 4; ++j) {
    int i = base + j;
    vals[j] = (i < n) ? cnt[i] : 0;
    s += vals[j];
  }
  int inc = s;
  for (int d = 1; d < 64; d <<= 1) {
    int x = __shfl_up(inc, d, 64);
    if (lane >= d) inc += x;
  }
  __shared__ int wsum[4];
  if (lane == 63) wsum[wv] = inc;
  __syncthreads();
  int wbase = 0;
  for (int w = 0; w < wv; ++w) wbase += wsum[w];
  int excl = wbase + (inc - s) + bsum[blockIdx.x];
  for (int j = 0; j < 4; ++j) {
    int i = base + j;
    if (i < n) off[i] = excl;
    excl += vals[j];
  }
}

// ---------------- CSR fill, 8-way partitioned cursors -----------------------
__global__ __launch_bounds__(256) void fill_csr8(const int* __restrict__ dst,
                                                 const int* __restrict__ src,
                                                 int* __restrict__ cur8,
                                                 int* __restrict__ csr, int N) {
  int t = blockIdx.x * 256 + threadIdx.x;
  if (t >= E_N) return;
  int p = blockIdx.x & 7;
  int pos = atomicAdd(&cur8[p * N + dst[t]], 1);
  csr[pos] = src[t];
}

// ---------------- gather-mean (bf16 in, bf16 mean out) ----------------------
// half-wave (32 lanes) per destination node; 8B/lane contiguous reads.
// CSR indices prefetched 32-at-a-time, broadcast via shfl; rows unrolled x4.
__global__ __launch_bounds__(256) void gather_mean(const int* __restrict__ off,
                                                   const int* __restrict__ cnt,
                                                   const int* __restrict__ csr,
                                                   const unsigned short* __restrict__ xb,
                                                   unsigned short* __restrict__ aggb,
                                                   int N) {
  long t = (long)blockIdx.x * 256 + threadIdx.x;
  int node = (int)(t >> 5);
  if (node >= N) return;
  int lane = (int)(t & 31);
  int o = off[node], c = cnt[node];
  float4 acc = make_float4(0.f, 0.f, 0.f, 0.f);
  for (int j0 = 0; j0 < c; j0 += 32) {
    int nj = c - j0;
    if (nj > 32) nj = 32;
    int sidx = (lane < nj) ? csr[o + j0 + lane] : 0;
    int j = 0;
    for (; j + 4 <= nj; j += 4) {
      int s0 = __shfl(sidx, j + 0, 32);
      int s1 = __shfl(sidx, j + 1, 32);
      int s2 = __shfl(sidx, j + 2, 32);
      int s3 = __shfl(sidx, j + 3, 32);
      u16x4 v0 = *(const u16x4*)(xb + (size_t)s0 * H_DIM + lane * 4);
      u16x4 v1 = *(const u16x4*)(xb + (size_t)s1 * H_DIM + lane * 4);
      u16x4 v2 = *(const u16x4*)(xb + (size_t)s2 * H_DIM + lane * 4);
      u16x4 v3 = *(const u16x4*)(xb + (size_t)s3 * H_DIM + lane * 4);
      acc.x += b2f(v0[0]); acc.y += b2f(v0[1]); acc.z += b2f(v0[2]); acc.w += b2f(v0[3]);
      acc.x += b2f(v1[0]); acc.y += b2f(v1[1]); acc.z += b2f(v1[2]); acc.w += b2f(v1[3]);
      acc.x += b2f(v2[0]); acc.y += b2f(v2[1]); acc.z += b2f(v2[2]); acc.w += b2f(v2[3]);
      acc.x += b2f(v3[0]); acc.y += b2f(v3[1]); acc.z += b2f(v3[2]); acc.w += b2f(v3[3]);
    }
    for (; j < nj; ++j) {
      int s = __shfl(sidx, j, 32);
      u16x4 v = *(const u16x4*)(xb + (size_t)s * H_DIM + lane * 4);
      acc.x += b2f(v[0]); acc.y += b2f(v[1]);
      acc.z += b2f(v[2]); acc.w += b2f(v[3]);
    }
  }
  float inv = 1.0f / (float)(c > 0 ? c : 1);
  u16x4 r;
  r[0] = f2b(acc.x * inv); r[1] = f2b(acc.y * inv);
  r[2] = f2b(acc.z * inv); r[3] = f2b(acc.w * inv);
  *(u16x4*)(aggb + (size_t)node * H_DIM + lane * 4) = r;
}

// ---------------- weight prep: W2t[col][k], k<128 -> w_l[k][col], else w_r ----
__global__ __launch_bounds__(256) void prep_w(const float* __restrict__ wl,
                                              const float* __restrict__ wr,
                                              short* __restrict__ W2) {
  int t = blockIdx.x * 256 + threadIdx.x;  // 128*256 = 32768
  int col = t >> 8, k = t & 255;
  float v = (k < 128) ? wl[k * 128 + col] : wr[(k - 128) * 128 + col];
  W2[col * 256 + k] = (short)f2b(v);
}

// ---------------- fused SAGE linear: out = act( mean@w_l + x@w_r + b ) -------
__global__ __launch_bounds__(256) void sage_gemm(const unsigned short* __restrict__ aggb,
                                                 const unsigned short* __restrict__ xb,
                                                 const short* __restrict__ W2,
                                                 const float* __restrict__ bias,
                                                 unsigned short* __restrict__ outb,
                                                 float* __restrict__ outf,
                                                 int N, int relu) {
  __shared__ short wlds[128 * 256];  // 64 KiB
  const int tid = threadIdx.x;
  for (int c = tid; c < 4096; c += 256) {
    int col = c >> 5, g = c & 31;
    uint4 v = *(const uint4*)(W2 + col * 256 + g * 8);
    *(uint4*)(&wlds[col * 256 + ((g ^ (col & 15)) * 8)]) = v;
  }
  __syncthreads();

  const int lane = tid & 63;
  const int wave = tid >> 6;
  const int q = lane >> 4;
  const int n16 = lane & 15;
  const int rowbase = blockIdx.x * 128 + wave * 32;

  const unsigned short* aptr[2];
  const unsigned short* xptr[2];
  for (int g = 0; g < 2; ++g) {
    int row = rowbase + g * 16 + n16;
    int rr = row < N ? row : 0;
    aptr[g] = aggb + (size_t)rr * H_DIM + q * 8;
    xptr[g] = xb + (size_t)rr * H_DIM + q * 8;
  }

  f32x4 acc[2][8] = {};

  for (int kt = 0; kt < 8; ++kt) {
    const int k0 = kt * 32;
    bh8 afrag[2];
    for (int g = 0; g < 2; ++g) {
      const unsigned short* p = (kt < 4) ? (aptr[g] + k0) : (xptr[g] + (k0 - 128));
      afrag[g] = *(const bh8*)(p);
    }
    const int swz = ((kt * 4 + q) ^ n16) * 8;
    for (int c = 0; c < 8; ++c) {
      bh8 b = *(const bh8*)(&wlds[(c * 16 + n16) * 256 + swz]);
      acc[0][c] = __builtin_amdgcn_mfma_f32_16x16x32_bf16(afrag[0], b, acc[0][c], 0, 0, 0);
      acc[1][c] = __builtin_amdgcn_mfma_f32_16x16x32_bf16(afrag[1], b, acc[1][c], 0, 0, 0);
    }
  }

  float bcol[8];
  for (int c = 0; c < 8; ++c) bcol[c] = bias[c * 16 + n16];

  for (int g = 0; g < 2; ++g) {
    for (int r = 0; r < 4; ++r) {
      int row = rowbase + g * 16 + q * 4 + r;
      if (row >= N) continue;
      for (int c = 0; c < 8; ++c) {
        float v = acc[g][c][r] + bcol[c];
        if (relu) v = v > 0.0f ? v : 0.0f;
        if (outb) outb[(size_t)row * H_DIM + c * 16 + n16] = f2b(v);
        else      outf[(size_t)row * H_DIM + c * 16 + n16] = v;
      }
    }
  }
}

// ---------------- final edge dot product (h2 fp32) ----------------
__global__ __launch_bounds__(256) void final_dot(const int* __restrict__ lbl,
                                                 const float* __restrict__ u2,
                                                 const float* __restrict__ i2,
                                                 float* __restrict__ out) {
  long t = (long)blockIdx.x * 256 + threadIdx.x;
  int e = (int)(t >> 5);
  if (e >= EL_N) return;
  int lane = (int)(t & 31);
  int lu = lbl[e];
  int li = lbl[EL_N + e];
  float4 a = *(const float4*)(u2 + (size_t)lu * H_DIM + lane * 4);
  float4 b = *(const float4*)(i2 + (size_t)li * H_DIM + lane * 4);
  float p = a.x * b.x + a.y * b.y + a.z * b.z + a.w * b.w;
  for (int off = 16; off > 0; off >>= 1) p += __shfl_down(p, off, 32);
  if (lane == 0) out[e] = p;
}

extern "C" void kernel_launch(void* const* d_in, const int* in_sizes, int n_in,
                              void* d_out, int out_size, void* d_ws, size_t ws_size,
                              hipStream_t stream) {
  const float* user_emb = (const float*)d_in[0];
  const float* item_emb = (const float*)d_in[1];
  const float* w1_ui_l = (const float*)d_in[2];
  const float* w1_ui_r = (const float*)d_in[3];
  const float* w1_iu_l = (const float*)d_in[4];
  const float* w1_iu_r = (const float*)d_in[5];
  const float* w2_ui_l = (const float*)d_in[6];
  const float* w2_ui_r = (const float*)d_in[7];
  const float* w2_iu_l = (const float*)d_in[8];
  const float* w2_iu_r = (const float*)d_in[9];
  const float* b1_ui = (const float*)d_in[10];
  const float* b1_iu = (const float*)d_in[11];
  const float* b2_ui = (const float*)d_in[12];
  const float* b2_iu = (const float*)d_in[13];
  const int* unid = (const int*)d_in[14];
  const int* inid = (const int*)d_in[15];
  const int* e_ui = (const int*)d_in[16];  // row0 users, row1 items
  const int* e_iu = (const int*)d_in[17];  // row0 items, row1 users
  const int* elbl = (const int*)d_in[18];  // row0 users, row1 items
  float* out = (float*)d_out;

  char* ws = (char*)d_ws;
  size_t o = 0;
  auto alloc = [&](size_t bytes) {
    char* p = ws + o;
    o = (o + bytes + 255) & ~(size_t)255;
    return p;
  };
  // zeroed region: 8-way partitioned histograms
  int* c8_u = (int*)alloc((size_t)8 * U_N * 4);
  int* c8_i = (int*)alloc((size_t)8 * I_N * 4);
  size_t zero_end = o;
  int* cnt_u = (int*)alloc((size_t)U_N * 4);
  int* cnt_i = (int*)alloc((size_t)I_N * 4);
  int* off_u = (int*)alloc((size_t)(U_N + 1) * 4);
  int* off_i = (int*)alloc((size_t)(I_N + 1) * 4);
  int* cur8_u = (int*)alloc((size_t)8 * U_N * 4);
  int* cur8_i = (int*)alloc((size_t)8 * I_N * 4);
  int* csr_u = (int*)alloc((size_t)E_N * 4);  // item srcs grouped by user dst
  int* csr_i = (int*)alloc((size_t)E_N * 4);  // user srcs grouped by item dst
  int* bsum_u = (int*)alloc(256 * 4);
  int* bsum_i = (int*)alloc(256 * 4);
  unsigned short* ue_b = (unsigned short*)alloc((size_t)U_N * H_DIM * 2);
  unsigned short* ie_b = (unsigned short*)alloc((size_t)I_N * H_DIM * 2);
  unsigned short* agg_u = (unsigned short*)alloc((size_t)U_N * H_DIM * 2);
  unsigned short* agg_i = (unsigned short*)alloc((size_t)I_N * H_DIM * 2);
  unsigned short* h1_u = (unsigned short*)alloc((size_t)U_N * H_DIM * 2);
  unsigned short* h1_i = (unsigned short*)alloc((size_t)I_N * H_DIM * 2);
  float* h2_u = (float*)alloc((size_t)U_N * H_DIM * 4);
  float* h2_i = (float*)alloc((size_t)I_N * H_DIM * 4);
  short* W2_1u = (short*)alloc(128 * 256 * 2);
  short* W2_1i = (short*)alloc(128 * 256 * 2);
  short* W2_2u = (short*)alloc(128 * 256 * 2);
  short* W2_2i = (short*)alloc(128 * 256 * 2);
  if (o > ws_size) {
    fprintf(stderr, "kernel_launch: ws too small, need %zu have %zu\n", o, ws_size);
    return;
  }

  const int nb_u = (U_N + 1023) / 1024;  // 98
  const int nb_i = (I_N + 1023) / 1024;  // 49

  hipMemsetAsync(d_ws, 0, zero_end, stream);
  count_deg8<<<(E_N + 255) / 256, 256, 0, stream>>>(e_ui, c8_u, c8_i);
  cvt_emb<<<(U_N * 16 + 255) / 256, 256, 0, stream>>>(user_emb, unid, ue_b, U_N);
  cvt_emb<<<(I_N * 16 + 255) / 256, 256, 0, stream>>>(item_emb, inid, ie_b, I_N);
  prep_w<<<128, 256, 0, stream>>>(w1_iu_l, w1_iu_r, W2_1u);
  prep_w<<<128, 256, 0, stream>>>(w1_ui_l, w1_ui_r, W2_1i);
  prep_w<<<128, 256, 0, stream>>>(w2_iu_l, w2_iu_r, W2_2u);
  prep_w<<<128, 256, 0, stream>>>(w2_ui_l, w2_ui_r, W2_2i);

  reduce_cnt<<<(U_N + 255) / 256, 256, 0, stream>>>(c8_u, cnt_u, U_N);
  reduce_cnt<<<(I_N + 255) / 256, 256, 0, stream>>>(c8_i, cnt_i, I_N);

  scan_p1<<<nb_u, 256, 0, stream>>>(cnt_u, bsum_u, U_N);
  scan_p1<<<nb_i, 256, 0, stream>>>(cnt_i, bsum_i, I_N);
  scan_p2<<<1, 256, 0, stream>>>(bsum_u, nb_u);
  scan_p2<<<1, 256, 0, stream>>>(bsum_i, nb_i);
  scan_p3<<<nb_u, 256, 0, stream>>>(cnt_u, bsum_u, off_u, U_N);
  scan_p3<<<nb_i, 256, 0, stream>>>(cnt_i, bsum_i, off_i, I_N);

  init_cur8<<<(U_N + 255) / 256, 256, 0, stream>>>(c8_u, off_u, cur8_u, U_N);
  init_cur8<<<(I_N + 255) / 256, 256, 0, stream>>>(c8_i, off_i, cur8_i, I_N);

  fill_csr8<<<(E_N + 255) / 256, 256, 0, stream>>>(e_ui, e_ui + E_N, cur8_u, csr_u, U_N);
  fill_csr8<<<(E_N + 255) / 256, 256, 0, stream>>>(e_ui + E_N, e_ui, cur8_i, csr_i, I_N);

  const int gu_blocks = (U_N * 32 + 255) / 256;
  const int gi_blocks = (I_N * 32 + 255) / 256;
  // layer 1: users <- items, items <- users (bf16 mean out)
  gather_mean<<<gu_blocks, 256, 0, stream>>>(off_u, cnt_u, csr_u, ie_b, agg_u, U_N);
  gather_mean<<<gi_blocks, 256, 0, stream>>>(off_i, cnt_i, csr_i, ue_b, agg_i, I_N);

  sage_gemm<<<(U_N + 127) / 128, 256, 0, stream>>>(agg_u, ue_b, W2_1u, b1_iu,
                                                   h1_u, nullptr, U_N, 1);
  sage_gemm<<<(I_N + 127) / 128, 256, 0, stream>>>(agg_i, ie_b, W2_1i, b1_ui,
                                                   h1_i, nullptr, I_N, 1);

  // layer 2 (reuse CSR)
  gather_mean<<<gu_blocks, 256, 0, stream>>>(off_u, cnt_u, csr_u, h1_i, agg_u, U_N);
  gather_mean<<<gi_blocks, 256, 0, stream>>>(off_i, cnt_i, csr_i, h1_u, agg_i, I_N);

  sage_gemm<<<(U_N + 127) / 128, 256, 0, stream>>>(agg_u, h1_u, W2_2u, b2_iu,
                                                   nullptr, h2_u, U_N, 0);
  sage_gemm<<<(I_N + 127) / 128, 256, 0, stream>>>(agg_i, h1_i, W2_2i, b2_ui,
                                                   nullptr, h2_i, I_N, 0);

  final_dot<<<(EL_N * 32 + 255) / 256, 256, 0, stream>>>(elbl, h2_u, h2_i, out);
}

// Round 6
// 450.479 us; speedup vs baseline: 9.7631x; 1.1497x over previous
//
#include <hip/hip_runtime.h>
#include <hip/hip_bf16.h>
#include <cstdio>

#define U_N 100000
#define I_N 50000
#define H_DIM 128
#define E_N 600000
#define EL_N 200000

#define EPB 2048                         // edges per block in binning passes
#define NBLK ((E_N + EPB - 1) / EPB)     // 293
#define SH_U 8
#define SH_I 7
#define NB_U ((U_N + 255) >> 8)          // 391
#define NB_I ((I_N + 127) >> 7)          // 391
#define LH_U (NB_U * NBLK)               // 114563
#define LH_I (NB_I * NBLK)

typedef __attribute__((ext_vector_type(8))) short bh8;
typedef __attribute__((ext_vector_type(4))) float f32x4;
typedef __attribute__((ext_vector_type(4))) unsigned short u16x4;
typedef __attribute__((ext_vector_type(8))) unsigned short u16x8;

// fp32 -> bf16 (RNE)
__device__ inline unsigned short f2b(float f) {
  unsigned u = __builtin_bit_cast(unsigned, f);
  u += 0x7fffu + ((u >> 16) & 1u);
  return (unsigned short)(u >> 16);
}
// bf16 bits -> fp32
__device__ inline float b2f(unsigned short h) {
  unsigned u = ((unsigned)h) << 16;
  return __builtin_bit_cast(float, u);
}

// ---------------- pass A: coarse-bin histogram (LDS atomics only) -----------
__global__ __launch_bounds__(256) void bin_hist(const int* __restrict__ dst,
                                                int* __restrict__ hist,
                                                int shift, int nbins) {
  __shared__ int h[512];
  const int t = threadIdx.x;
  for (int i = t; i < nbins; i += 256) h[i] = 0;
  __syncthreads();
  const int base = blockIdx.x * EPB;
  const int end = min(base + EPB, E_N);
  for (int i = base + t; i < end; i += 256)
    atomicAdd(&h[((unsigned)dst[i]) >> shift], 1);
  __syncthreads();
  for (int i = t; i < nbins; i += 256)
    hist[i * NBLK + blockIdx.x] = h[i];
}

// ---------------- pass B: scatter packed (dstlo|src) into coarse buckets ----
__global__ __launch_bounds__(256) void bin_scatter(const int* __restrict__ dst,
                                                   const int* __restrict__ src,
                                                   const int* __restrict__ hoff,
                                                   unsigned* __restrict__ bucketed,
                                                   int shift, int nbins) {
  __shared__ int cur[512];
  const int t = threadIdx.x;
  for (int i = t; i < nbins; i += 256) cur[i] = hoff[i * NBLK + blockIdx.x];
  __syncthreads();
  const int base = blockIdx.x * EPB;
  const int end = min(base + EPB, E_N);
  const unsigned mask = (1u << shift) - 1u;
  for (int i = base + t; i < end; i += 256) {
    unsigned d = (unsigned)dst[i];
    int bin = (int)(d >> shift);
    int pos = atomicAdd(&cur[bin], 1);
    bucketed[pos] = ((d & mask) << 24) | (unsigned)src[i];
  }
}

// ---------------- pass C: group bucket by exact dst -> csr, cnt, off --------
__global__ __launch_bounds__(256) void bin_group(const int* __restrict__ hoff,
                                                 const unsigned* __restrict__ bucketed,
                                                 int* __restrict__ csr,
                                                 int* __restrict__ cnt,
                                                 int* __restrict__ off,
                                                 int shift, int nbins, int N) {
  __shared__ int cl[256];
  __shared__ int cur[256];
  __shared__ int wsum[4];
  const int b = blockIdx.x;
  const int t = threadIdx.x;
  const int start = hoff[b * NBLK];
  const int end = (b + 1 < nbins) ? hoff[(b + 1) * NBLK] : E_N;
  const int ndst = 1 << shift;   // 256 (users) or 128 (items)
  const int base = b << shift;
  if (t < ndst) cl[t] = 0;
  __syncthreads();
  for (int i = start + t; i < end; i += 256)
    atomicAdd(&cl[bucketed[i] >> 24], 1);
  __syncthreads();
  // exclusive scan of cl[0..ndst)
  int v = (t < ndst) ? cl[t] : 0;
  const int lane = t & 63, wv = t >> 6;
  int inc = v;
  for (int d = 1; d < 64; d <<= 1) {
    int x = __shfl_up(inc, d, 64);
    if (lane >= d) inc += x;
  }
  if (lane == 63) wsum[wv] = inc;
  __syncthreads();
  int wbase = 0;
  for (int q = 0; q < wv; ++q) wbase += wsum[q];
  int excl = wbase + inc - v;
  if (t < ndst) {
    cur[t] = start + excl;
    int node = base + t;
    if (node < N) { cnt[node] = v; off[node] = start + excl; }
  }
  __syncthreads();
  for (int i = start + t; i < end; i += 256) {
    unsigned w = bucketed[i];
    int pos = atomicAdd(&cur[w >> 24], 1);
    csr[pos] = (int)(w & 0xFFFFFFu);
  }
}

// ---------------- embedding convert (applies node_id gather) ----------------
__global__ __launch_bounds__(256) void cvt_emb(const float* __restrict__ x,
                                               const int* __restrict__ nid,
                                               unsigned short* __restrict__ xb,
                                               int N) {
  int t = blockIdx.x * 256 + threadIdx.x;  // N*16 threads, 8 elems each
  if (t >= N * 16) return;
  int row = t >> 4, seg = t & 15;
  int r = nid ? nid[row] : row;
  const float* p = x + (size_t)r * H_DIM + seg * 8;
  float4 a = ((const float4*)p)[0];
  float4 b = ((const float4*)p)[1];
  u16x8 v;
  v[0] = f2b(a.x); v[1] = f2b(a.y); v[2] = f2b(a.z); v[3] = f2b(a.w);
  v[4] = f2b(b.x); v[5] = f2b(b.y); v[6] = f2b(b.z); v[7] = f2b(b.w);
  *(u16x8*)(xb + (size_t)row * H_DIM + seg * 8) = v;
}

// ---------------- hierarchical exclusive scan --------------------------------
__global__ __launch_bounds__(256) void scan_p1(const int* __restrict__ cnt,
                                               int* __restrict__ bsum, int n) {
  const int t = threadIdx.x;
  const int base = blockIdx.x * 1024 + t * 4;
  int s = 0;
  for (int j = 0; j < 4; ++j) {
    int i = base + j;
    if (i < n) s += cnt[i];
  }
  for (int off = 32; off > 0; off >>= 1) s += __shfl_down(s, off, 64);
  __shared__ int wsum[4];
  if ((t & 63) == 0) wsum[t >> 6] = s;
  __syncthreads();
  if (t == 0) bsum[blockIdx.x] = wsum[0] + wsum[1] + wsum[2] + wsum[3];
}

__global__ __launch_bounds__(256) void scan_p2(int* __restrict__ bsum, int nb) {
  __shared__ int sm[256];
  const int t = threadIdx.x;
  int v = (t < nb) ? bsum[t] : 0;
  sm[t] = v;
  __syncthreads();
  for (int d = 1; d < 256; d <<= 1) {
    int x = (t >= d) ? sm[t - d] : 0;
    __syncthreads();
    sm[t] += x;
    __syncthreads();
  }
  if (t < nb) bsum[t] = sm[t] - v;  // exclusive
}

__global__ __launch_bounds__(256) void scan_p3(const int* __restrict__ cnt,
                                               const int* __restrict__ bsum,
                                               int* __restrict__ off, int n) {
  const int t = threadIdx.x;
  const int lane = t & 63, wv = t >> 6;
  const int base = blockIdx.x * 1024 + t * 4;
  int vals[4];
  int s = 0;
  for (int j = 0; j < 4; ++j) {
    int i = base + j;
    vals[j] = (i < n) ? cnt[i] : 0;
    s += vals[j];
  }
  int inc = s;
  for (int d = 1; d < 64; d <<= 1) {
    int x = __shfl_up(inc, d, 64);
    if (lane >= d) inc += x;
  }
  __shared__ int wsum[4];
  if (lane == 63) wsum[wv] = inc;
  __syncthreads();
  int wbase = 0;
  for (int w = 0; w < wv; ++w) wbase += wsum[w];
  int excl = wbase + (inc - s) + bsum[blockIdx.x];
  for (int j = 0; j < 4; ++j) {
    int i = base + j;
    if (i < n) off[i] = excl;
    excl += vals[j];
  }
}

// ---------------- gather-mean (bf16 in, bf16 mean out) ----------------------
__global__ __launch_bounds__(256) void gather_mean(const int* __restrict__ off,
                                                   const int* __restrict__ cnt,
                                                   const int* __restrict__ csr,
                                                   const unsigned short* __restrict__ xb,
                                                   unsigned short* __restrict__ aggb,
                                                   int N) {
  long t = (long)blockIdx.x * 256 + threadIdx.x;
  int node = (int)(t >> 5);
  if (node >= N) return;
  int lane = (int)(t & 31);
  int o = off[node], c = cnt[node];
  float4 acc = make_float4(0.f, 0.f, 0.f, 0.f);
  for (int j0 = 0; j0 < c; j0 += 32) {
    int nj = c - j0;
    if (nj > 32) nj = 32;
    int sidx = (lane < nj) ? csr[o + j0 + lane] : 0;
    int j = 0;
    for (; j + 4 <= nj; j += 4) {
      int s0 = __shfl(sidx, j + 0, 32);
      int s1 = __shfl(sidx, j + 1, 32);
      int s2 = __shfl(sidx, j + 2, 32);
      int s3 = __shfl(sidx, j + 3, 32);
      u16x4 v0 = *(const u16x4*)(xb + (size_t)s0 * H_DIM + lane * 4);
      u16x4 v1 = *(const u16x4*)(xb + (size_t)s1 * H_DIM + lane * 4);
      u16x4 v2 = *(const u16x4*)(xb + (size_t)s2 * H_DIM + lane * 4);
      u16x4 v3 = *(const u16x4*)(xb + (size_t)s3 * H_DIM + lane * 4);
      acc.x += b2f(v0[0]); acc.y += b2f(v0[1]); acc.z += b2f(v0[2]); acc.w += b2f(v0[3]);
      acc.x += b2f(v1[0]); acc.y += b2f(v1[1]); acc.z += b2f(v1[2]); acc.w += b2f(v1[3]);
      acc.x += b2f(v2[0]); acc.y += b2f(v2[1]); acc.z += b2f(v2[2]); acc.w += b2f(v2[3]);
      acc.x += b2f(v3[0]); acc.y += b2f(v3[1]); acc.z += b2f(v3[2]); acc.w += b2f(v3[3]);
    }
    for (; j < nj; ++j) {
      int s = __shfl(sidx, j, 32);
      u16x4 v = *(const u16x4*)(xb + (size_t)s * H_DIM + lane * 4);
      acc.x += b2f(v[0]); acc.y += b2f(v[1]);
      acc.z += b2f(v[2]); acc.w += b2f(v[3]);
    }
  }
  float inv = 1.0f / (float)(c > 0 ? c : 1);
  u16x4 r;
  r[0] = f2b(acc.x * inv); r[1] = f2b(acc.y * inv);
  r[2] = f2b(acc.z * inv); r[3] = f2b(acc.w * inv);
  *(u16x4*)(aggb + (size_t)node * H_DIM + lane * 4) = r;
}

// ---------------- weight prep: W2t[col][k], k<128 -> w_l[k][col], else w_r ----
__global__ __launch_bounds__(256) void prep_w(const float* __restrict__ wl,
                                              const float* __restrict__ wr,
                                              short* __restrict__ W2) {
  int t = blockIdx.x * 256 + threadIdx.x;  // 128*256 = 32768
  int col = t >> 8, k = t & 255;
  float v = (k < 128) ? wl[k * 128 + col] : wr[(k - 128) * 128 + col];
  W2[col * 256 + k] = (short)f2b(v);
}

// ---------------- fused SAGE linear: out = act( mean@w_l + x@w_r + b ) -------
__global__ __launch_bounds__(256) void sage_gemm(const unsigned short* __restrict__ aggb,
                                                 const unsigned short* __restrict__ xb,
                                                 const short* __restrict__ W2,
                                                 const float* __restrict__ bias,
                                                 unsigned short* __restrict__ outb,
                                                 float* __restrict__ outf,
                                                 int N, int relu) {
  __shared__ short wlds[128 * 256];  // 64 KiB
  const int tid = threadIdx.x;
  for (int c = tid; c < 4096; c += 256) {
    int col = c >> 5, g = c & 31;
    uint4 v = *(const uint4*)(W2 + col * 256 + g * 8);
    *(uint4*)(&wlds[col * 256 + ((g ^ (col & 15)) * 8)]) = v;
  }
  __syncthreads();

  const int lane = tid & 63;
  const int wave = tid >> 6;
  const int q = lane >> 4;
  const int n16 = lane & 15;
  const int rowbase = blockIdx.x * 128 + wave * 32;

  const unsigned short* aptr[2];
  const unsigned short* xptr[2];
  for (int g = 0; g < 2; ++g) {
    int row = rowbase + g * 16 + n16;
    int rr = row < N ? row : 0;
    aptr[g] = aggb + (size_t)rr * H_DIM + q * 8;
    xptr[g] = xb + (size_t)rr * H_DIM + q * 8;
  }

  f32x4 acc[2][8] = {};

  for (int kt = 0; kt < 8; ++kt) {
    const int k0 = kt * 32;
    bh8 afrag[2];
    for (int g = 0; g < 2; ++g) {
      const unsigned short* p = (kt < 4) ? (aptr[g] + k0) : (xptr[g] + (k0 - 128));
      afrag[g] = *(const bh8*)(p);
    }
    const int swz = ((kt * 4 + q) ^ n16) * 8;
    for (int c = 0; c < 8; ++c) {
      bh8 b = *(const bh8*)(&wlds[(c * 16 + n16) * 256 + swz]);
      acc[0][c] = __builtin_amdgcn_mfma_f32_16x16x32_bf16(afrag[0], b, acc[0][c], 0, 0, 0);
      acc[1][c] = __builtin_amdgcn_mfma_f32_16x16x32_bf16(afrag[1], b, acc[1][c], 0, 0, 0);
    }
  }

  float bcol[8];
  for (int c = 0; c < 8; ++c) bcol[c] = bias[c * 16 + n16];

  for (int g = 0; g < 2; ++g) {
    for (int r = 0; r < 4; ++r) {
      int row = rowbase + g * 16 + q * 4 + r;
      if (row >= N) continue;
      for (int c = 0; c < 8; ++c) {
        float v = acc[g][c][r] + bcol[c];
        if (relu) v = v > 0.0f ? v : 0.0f;
        if (outb) outb[(size_t)row * H_DIM + c * 16 + n16] = f2b(v);
        else      outf[(size_t)row * H_DIM + c * 16 + n16] = v;
      }
    }
  }
}

// ---------------- final edge dot product (h2 fp32) ----------------
__global__ __launch_bounds__(256) void final_dot(const int* __restrict__ lbl,
                                                 const float* __restrict__ u2,
                                                 const float* __restrict__ i2,
                                                 float* __restrict__ out) {
  long t = (long)blockIdx.x * 256 + threadIdx.x;
  int e = (int)(t >> 5);
  if (e >= EL_N) return;
  int lane = (int)(t & 31);
  int lu = lbl[e];
  int li = lbl[EL_N + e];
  float4 a = *(const float4*)(u2 + (size_t)lu * H_DIM + lane * 4);
  float4 b = *(const float4*)(i2 + (size_t)li * H_DIM + lane * 4);
  float p = a.x * b.x + a.y * b.y + a.z * b.z + a.w * b.w;
  for (int off = 16; off > 0; off >>= 1) p += __shfl_down(p, off, 32);
  if (lane == 0) out[e] = p;
}

extern "C" void kernel_launch(void* const* d_in, const int* in_sizes, int n_in,
                              void* d_out, int out_size, void* d_ws, size_t ws_size,
                              hipStream_t stream) {
  const float* user_emb = (const float*)d_in[0];
  const float* item_emb = (const float*)d_in[1];
  const float* w1_ui_l = (const float*)d_in[2];
  const float* w1_ui_r = (const float*)d_in[3];
  const float* w1_iu_l = (const float*)d_in[4];
  const float* w1_iu_r = (const float*)d_in[5];
  const float* w2_ui_l = (const float*)d_in[6];
  const float* w2_ui_r = (const float*)d_in[7];
  const float* w2_iu_l = (const float*)d_in[8];
  const float* w2_iu_r = (const float*)d_in[9];
  const float* b1_ui = (const float*)d_in[10];
  const float* b1_iu = (const float*)d_in[11];
  const float* b2_ui = (const float*)d_in[12];
  const float* b2_iu = (const float*)d_in[13];
  const int* unid = (const int*)d_in[14];
  const int* inid = (const int*)d_in[15];
  const int* e_ui = (const int*)d_in[16];  // row0 users, row1 items
  const int* e_iu = (const int*)d_in[17];  // row0 items, row1 users
  const int* elbl = (const int*)d_in[18];  // row0 users, row1 items
  float* out = (float*)d_out;

  char* ws = (char*)d_ws;
  size_t o = 0;
  auto alloc = [&](size_t bytes) {
    char* p = ws + o;
    o = (o + bytes + 255) & ~(size_t)255;
    return p;
  };
  int* hist_u = (int*)alloc((size_t)LH_U * 4);
  int* hoff_u = (int*)alloc((size_t)LH_U * 4);
  int* hist_i = (int*)alloc((size_t)LH_I * 4);
  int* hoff_i = (int*)alloc((size_t)LH_I * 4);
  unsigned* bkt_u = (unsigned*)alloc((size_t)E_N * 4);
  unsigned* bkt_i = (unsigned*)alloc((size_t)E_N * 4);
  int* cnt_u = (int*)alloc((size_t)U_N * 4);
  int* cnt_i = (int*)alloc((size_t)I_N * 4);
  int* off_u = (int*)alloc((size_t)U_N * 4);
  int* off_i = (int*)alloc((size_t)I_N * 4);
  int* csr_u = (int*)alloc((size_t)E_N * 4);  // item srcs grouped by user dst
  int* csr_i = (int*)alloc((size_t)E_N * 4);  // user srcs grouped by item dst
  int* bsum_u = (int*)alloc(256 * 4);
  int* bsum_i = (int*)alloc(256 * 4);
  unsigned short* ue_b = (unsigned short*)alloc((size_t)U_N * H_DIM * 2);
  unsigned short* ie_b = (unsigned short*)alloc((size_t)I_N * H_DIM * 2);
  unsigned short* agg_u = (unsigned short*)alloc((size_t)U_N * H_DIM * 2);
  unsigned short* agg_i = (unsigned short*)alloc((size_t)I_N * H_DIM * 2);
  unsigned short* h1_u = (unsigned short*)alloc((size_t)U_N * H_DIM * 2);
  unsigned short* h1_i = (unsigned short*)alloc((size_t)I_N * H_DIM * 2);
  float* h2_u = (float*)alloc((size_t)U_N * H_DIM * 4);
  float* h2_i = (float*)alloc((size_t)I_N * H_DIM * 4);
  short* W2_1u = (short*)alloc(128 * 256 * 2);
  short* W2_1i = (short*)alloc(128 * 256 * 2);
  short* W2_2u = (short*)alloc(128 * 256 * 2);
  short* W2_2i = (short*)alloc(128 * 256 * 2);
  if (o > ws_size) {
    fprintf(stderr, "kernel_launch: ws too small, need %zu have %zu\n", o, ws_size);
    return;
  }

  // independent prep
  cvt_emb<<<(U_N * 16 + 255) / 256, 256, 0, stream>>>(user_emb, unid, ue_b, U_N);
  cvt_emb<<<(I_N * 16 + 255) / 256, 256, 0, stream>>>(item_emb, inid, ie_b, I_N);
  prep_w<<<128, 256, 0, stream>>>(w1_iu_l, w1_iu_r, W2_1u);
  prep_w<<<128, 256, 0, stream>>>(w1_ui_l, w1_ui_r, W2_1i);
  prep_w<<<128, 256, 0, stream>>>(w2_iu_l, w2_iu_r, W2_2u);
  prep_w<<<128, 256, 0, stream>>>(w2_ui_l, w2_ui_r, W2_2i);

  // CSR build, atomic-free (global side)
  bin_hist<<<NBLK, 256, 0, stream>>>(e_ui, hist_u, SH_U, NB_U);
  bin_hist<<<NBLK, 256, 0, stream>>>(e_ui + E_N, hist_i, SH_I, NB_I);

  scan_p1<<<(LH_U + 1023) / 1024, 256, 0, stream>>>(hist_u, bsum_u, LH_U);
  scan_p1<<<(LH_I + 1023) / 1024, 256, 0, stream>>>(hist_i, bsum_i, LH_I);
  scan_p2<<<1, 256, 0, stream>>>(bsum_u, (LH_U + 1023) / 1024);
  scan_p2<<<1, 256, 0, stream>>>(bsum_i, (LH_I + 1023) / 1024);
  scan_p3<<<(LH_U + 1023) / 1024, 256, 0, stream>>>(hist_u, bsum_u, hoff_u, LH_U);
  scan_p3<<<(LH_I + 1023) / 1024, 256, 0, stream>>>(hist_i, bsum_i, hoff_i, LH_I);

  bin_scatter<<<NBLK, 256, 0, stream>>>(e_ui, e_ui + E_N, hoff_u, bkt_u, SH_U, NB_U);
  bin_scatter<<<NBLK, 256, 0, stream>>>(e_ui + E_N, e_ui, hoff_i, bkt_i, SH_I, NB_I);

  bin_group<<<NB_U, 256, 0, stream>>>(hoff_u, bkt_u, csr_u, cnt_u, off_u, SH_U, NB_U, U_N);
  bin_group<<<NB_I, 256, 0, stream>>>(hoff_i, bkt_i, csr_i, cnt_i, off_i, SH_I, NB_I, I_N);

  const int gu_blocks = (U_N * 32 + 255) / 256;
  const int gi_blocks = (I_N * 32 + 255) / 256;
  // layer 1: users <- items, items <- users (bf16 mean out)
  gather_mean<<<gu_blocks, 256, 0, stream>>>(off_u, cnt_u, csr_u, ie_b, agg_u, U_N);
  gather_mean<<<gi_blocks, 256, 0, stream>>>(off_i, cnt_i, csr_i, ue_b, agg_i, I_N);

  sage_gemm<<<(U_N + 127) / 128, 256, 0, stream>>>(agg_u, ue_b, W2_1u, b1_iu,
                                                   h1_u, nullptr, U_N, 1);
  sage_gemm<<<(I_N + 127) / 128, 256, 0, stream>>>(agg_i, ie_b, W2_1i, b1_ui,
                                                   h1_i, nullptr, I_N, 1);

  // layer 2 (reuse CSR)
  gather_mean<<<gu_blocks, 256, 0, stream>>>(off_u, cnt_u, csr_u, h1_i, agg_u, U_N);
  gather_mean<<<gi_blocks, 256, 0, stream>>>(off_i, cnt_i, csr_i, h1_u, agg_i, I_N);

  sage_gemm<<<(U_N + 127) / 128, 256, 0, stream>>>(agg_u, h1_u, W2_2u, b2_iu,
                                                   nullptr, h2_u, U_N, 0);
  sage_gemm<<<(I_N + 127) / 128, 256, 0, stream>>>(agg_i, h1_i, W2_2i, b2_ui,
                                                   nullptr, h2_i, I_N, 0);

  final_dot<<<(EL_N * 32 + 255) / 256, 256, 0, stream>>>(elbl, h2_u, h2_i, out);
}

// Round 7
// 391.701 us; speedup vs baseline: 11.2282x; 1.1501x over previous
//
#include <hip/hip_runtime.h>
#include <hip/hip_bf16.h>
#include <cstdio>

#define U_N 100000
#define I_N 50000
#define H_DIM 128
#define E_N 600000
#define EL_N 200000

#define EPB 2048                         // edges per block in binning passes
#define NBLK ((E_N + EPB - 1) / EPB)     // 293
#define SH_U 8
#define SH_I 7
#define NB_U ((U_N + 255) >> 8)          // 391
#define NB_I ((I_N + 127) >> 7)          // 391
#define LH_U (NB_U * NBLK)               // 114563
#define LH_I (NB_I * NBLK)

#define NBLK_GU ((U_N + 127) / 128)      // 782
#define NBLK_GI ((I_N + 127) / 128)      // 391

typedef __attribute__((ext_vector_type(8))) short bh8;
typedef __attribute__((ext_vector_type(4))) float f32x4;
typedef __attribute__((ext_vector_type(8))) unsigned short u16x8;

// fp32 -> bf16 (RNE)
__device__ inline unsigned short f2b(float f) {
  unsigned u = __builtin_bit_cast(unsigned, f);
  u += 0x7fffu + ((u >> 16) & 1u);
  return (unsigned short)(u >> 16);
}
// bf16 bits -> fp32
__device__ inline float b2f(unsigned short h) {
  unsigned u = ((unsigned)h) << 16;
  return __builtin_bit_cast(float, u);
}

// ---------------- pass A: coarse-bin histogram (LDS atomics only) -----------
__global__ __launch_bounds__(256) void bin_hist(const int* __restrict__ dst,
                                                int* __restrict__ hist,
                                                int shift, int nbins) {
  __shared__ int h[512];
  const int t = threadIdx.x;
  for (int i = t; i < nbins; i += 256) h[i] = 0;
  __syncthreads();
  const int base = blockIdx.x * EPB;
  const int end = min(base + EPB, E_N);
  for (int i = base + t; i < end; i += 256)
    atomicAdd(&h[((unsigned)dst[i]) >> shift], 1);
  __syncthreads();
  for (int i = t; i < nbins; i += 256)
    hist[i * NBLK + blockIdx.x] = h[i];
}

// ---------------- pass B: scatter packed (dstlo|src) into coarse buckets ----
__global__ __launch_bounds__(256) void bin_scatter(const int* __restrict__ dst,
                                                   const int* __restrict__ src,
                                                   const int* __restrict__ hoff,
                                                   unsigned* __restrict__ bucketed,
                                                   int shift, int nbins) {
  __shared__ int cur[512];
  const int t = threadIdx.x;
  for (int i = t; i < nbins; i += 256) cur[i] = hoff[i * NBLK + blockIdx.x];
  __syncthreads();
  const int base = blockIdx.x * EPB;
  const int end = min(base + EPB, E_N);
  const unsigned mask = (1u << shift) - 1u;
  for (int i = base + t; i < end; i += 256) {
    unsigned d = (unsigned)dst[i];
    int bin = (int)(d >> shift);
    int pos = atomicAdd(&cur[bin], 1);
    bucketed[pos] = ((d & mask) << 24) | (unsigned)src[i];
  }
}

// ---------------- pass C: group bucket by exact dst -> csr, cnt, off --------
__global__ __launch_bounds__(256) void bin_group(const int* __restrict__ hoff,
                                                 const unsigned* __restrict__ bucketed,
                                                 int* __restrict__ csr,
                                                 int* __restrict__ cnt,
                                                 int* __restrict__ off,
                                                 int shift, int nbins, int N) {
  __shared__ int cl[256];
  __shared__ int cur[256];
  __shared__ int wsum[4];
  const int b = blockIdx.x;
  const int t = threadIdx.x;
  const int start = hoff[b * NBLK];
  const int end = (b + 1 < nbins) ? hoff[(b + 1) * NBLK] : E_N;
  const int ndst = 1 << shift;   // 256 (users) or 128 (items)
  const int base = b << shift;
  if (t < ndst) cl[t] = 0;
  __syncthreads();
  for (int i = start + t; i < end; i += 256)
    atomicAdd(&cl[bucketed[i] >> 24], 1);
  __syncthreads();
  // exclusive scan of cl[0..ndst)
  int v = (t < ndst) ? cl[t] : 0;
  const int lane = t & 63, wv = t >> 6;
  int inc = v;
  for (int d = 1; d < 64; d <<= 1) {
    int x = __shfl_up(inc, d, 64);
    if (lane >= d) inc += x;
  }
  if (lane == 63) wsum[wv] = inc;
  __syncthreads();
  int wbase = 0;
  for (int q = 0; q < wv; ++q) wbase += wsum[q];
  int excl = wbase + inc - v;
  if (t < ndst) {
    cur[t] = start + excl;
    int node = base + t;
    if (node < N) { cnt[node] = v; off[node] = start + excl; }
  }
  __syncthreads();
  for (int i = start + t; i < end; i += 256) {
    unsigned w = bucketed[i];
    int pos = atomicAdd(&cur[w >> 24], 1);
    csr[pos] = (int)(w & 0xFFFFFFu);
  }
}

// ---------------- embedding convert, both sides (applies node_id gather) ----
__global__ __launch_bounds__(256) void cvt_emb2(const float* __restrict__ xu,
                                                const float* __restrict__ xi,
                                                const int* __restrict__ unid,
                                                const int* __restrict__ inid,
                                                unsigned short* __restrict__ ub,
                                                unsigned short* __restrict__ ib) {
  int t = blockIdx.x * 256 + threadIdx.x;  // (U+I)*16 threads, 8 elems each
  const float* x;
  unsigned short* xb;
  int row, seg;
  if (t < U_N * 16) {
    row = t >> 4; seg = t & 15;
    row = unid ? unid[row] : row;
    x = xu; xb = ub + ((size_t)(t >> 4)) * H_DIM;
  } else {
    int t2 = t - U_N * 16;
    if (t2 >= I_N * 16) return;
    row = t2 >> 4; seg = t2 & 15;
    int r0 = row;
    row = inid ? inid[row] : row;
    x = xi; xb = ib + (size_t)r0 * H_DIM;
  }
  const float* p = x + (size_t)row * H_DIM + seg * 8;
  float4 a = ((const float4*)p)[0];
  float4 b = ((const float4*)p)[1];
  u16x8 v;
  v[0] = f2b(a.x); v[1] = f2b(a.y); v[2] = f2b(a.z); v[3] = f2b(a.w);
  v[4] = f2b(b.x); v[5] = f2b(b.y); v[6] = f2b(b.z); v[7] = f2b(b.w);
  *(u16x8*)(xb + seg * 8) = v;
}

// ---------------- hierarchical exclusive scan --------------------------------
__global__ __launch_bounds__(256) void scan_p1(const int* __restrict__ cnt,
                                               int* __restrict__ bsum, int n) {
  const int t = threadIdx.x;
  const int base = blockIdx.x * 1024 + t * 4;
  int s = 0;
  for (int j = 0; j < 4; ++j) {
    int i = base + j;
    if (i < n) s += cnt[i];
  }
  for (int off = 32; off > 0; off >>= 1) s += __shfl_down(s, off, 64);
  __shared__ int wsum[4];
  if ((t & 63) == 0) wsum[t >> 6] = s;
  __syncthreads();
  if (t == 0) bsum[blockIdx.x] = wsum[0] + wsum[1] + wsum[2] + wsum[3];
}

__global__ __launch_bounds__(256) void scan_p2(int* __restrict__ bsum, int nb) {
  __shared__ int sm[256];
  const int t = threadIdx.x;
  int v = (t < nb) ? bsum[t] : 0;
  sm[t] = v;
  __syncthreads();
  for (int d = 1; d < 256; d <<= 1) {
    int x = (t >= d) ? sm[t - d] : 0;
    __syncthreads();
    sm[t] += x;
    __syncthreads();
  }
  if (t < nb) bsum[t] = sm[t] - v;  // exclusive
}

__global__ __launch_bounds__(256) void scan_p3(const int* __restrict__ cnt,
                                               const int* __restrict__ bsum,
                                               int* __restrict__ off, int n) {
  const int t = threadIdx.x;
  const int lane = t & 63, wv = t >> 6;
  const int base = blockIdx.x * 1024 + t * 4;
  int vals[4];
  int s = 0;
  for (int j = 0; j < 4; ++j) {
    int i = base + j;
    vals[j] = (i < n) ? cnt[i] : 0;
    s += vals[j];
  }
  int inc = s;
  for (int d = 1; d < 64; d <<= 1) {
    int x = __shfl_up(inc, d, 64);
    if (lane >= d) inc += x;
  }
  __shared__ int wsum[4];
  if (lane == 63) wsum[wv] = inc;
  __syncthreads();
  int wbase = 0;
  for (int w = 0; w < wv; ++w) wbase += wsum[w];
  int excl = wbase + (inc - s) + bsum[blockIdx.x];
  for (int j = 0; j < 4; ++j) {
    int i = base + j;
    if (i < n) off[i] = excl;
    excl += vals[j];
  }
}

// ---------------- gather-mean, both sides (bf16 in, bf16 mean out) ----------
// 16-lane group per destination node; 16B/lane (u16x8) reads; x4 ILP unroll.
__global__ __launch_bounds__(256) void gather_mean2(
    const int* __restrict__ off_u, const int* __restrict__ cnt_u,
    const int* __restrict__ csr_u, const unsigned short* __restrict__ xsrc_u,
    unsigned short* __restrict__ agg_u,
    const int* __restrict__ off_i, const int* __restrict__ cnt_i,
    const int* __restrict__ csr_i, const unsigned short* __restrict__ xsrc_i,
    unsigned short* __restrict__ agg_i) {
  long t = (long)blockIdx.x * 256 + threadIdx.x;
  int node = (int)(t >> 4);
  int lane = (int)(t & 15);
  const int* off; const int* cnt; const int* csr;
  const unsigned short* xb; unsigned short* aggb;
  if (node < U_N) {
    off = off_u; cnt = cnt_u; csr = csr_u; xb = xsrc_u; aggb = agg_u;
  } else {
    node -= U_N;
    if (node >= I_N) return;
    off = off_i; cnt = cnt_i; csr = csr_i; xb = xsrc_i; aggb = agg_i;
  }
  int o = off[node], c = cnt[node];
  float acc[8] = {};
  for (int j0 = 0; j0 < c; j0 += 16) {
    int nj = c - j0;
    if (nj > 16) nj = 16;
    int sidx = (lane < nj) ? csr[o + j0 + lane] : 0;
    int j = 0;
    for (; j + 4 <= nj; j += 4) {
      int s0 = __shfl(sidx, j + 0, 16);
      int s1 = __shfl(sidx, j + 1, 16);
      int s2 = __shfl(sidx, j + 2, 16);
      int s3 = __shfl(sidx, j + 3, 16);
      u16x8 v0 = *(const u16x8*)(xb + (size_t)s0 * H_DIM + lane * 8);
      u16x8 v1 = *(const u16x8*)(xb + (size_t)s1 * H_DIM + lane * 8);
      u16x8 v2 = *(const u16x8*)(xb + (size_t)s2 * H_DIM + lane * 8);
      u16x8 v3 = *(const u16x8*)(xb + (size_t)s3 * H_DIM + lane * 8);
      for (int k = 0; k < 8; ++k) acc[k] += b2f(v0[k]);
      for (int k = 0; k < 8; ++k) acc[k] += b2f(v1[k]);
      for (int k = 0; k < 8; ++k) acc[k] += b2f(v2[k]);
      for (int k = 0; k < 8; ++k) acc[k] += b2f(v3[k]);
    }
    for (; j < nj; ++j) {
      int s = __shfl(sidx, j, 16);
      u16x8 v = *(const u16x8*)(xb + (size_t)s * H_DIM + lane * 8);
      for (int k = 0; k < 8; ++k) acc[k] += b2f(v[k]);
    }
  }
  float inv = 1.0f / (float)(c > 0 ? c : 1);
  u16x8 r;
  for (int k = 0; k < 8; ++k) r[k] = f2b(acc[k] * inv);
  *(u16x8*)(aggb + (size_t)node * H_DIM + lane * 8) = r;
}

// ---------------- weight prep, all 4 matrices -------------------------------
// W2t[col][k]: k<128 -> w_l[k][col], else w_r[k-128][col]
__global__ __launch_bounds__(256) void prep_w4(
    const float* __restrict__ l0, const float* __restrict__ r0, short* __restrict__ o0,
    const float* __restrict__ l1, const float* __restrict__ r1, short* __restrict__ o1,
    const float* __restrict__ l2, const float* __restrict__ r2, short* __restrict__ o2,
    const float* __restrict__ l3, const float* __restrict__ r3, short* __restrict__ o3) {
  int t = blockIdx.x * 256 + threadIdx.x;  // 4*32768
  int set = t >> 15, s = t & 32767;
  const float *wl, *wr; short* W2;
  if (set == 0)      { wl = l0; wr = r0; W2 = o0; }
  else if (set == 1) { wl = l1; wr = r1; W2 = o1; }
  else if (set == 2) { wl = l2; wr = r2; W2 = o2; }
  else               { wl = l3; wr = r3; W2 = o3; }
  int col = s >> 8, k = s & 255;
  float v = (k < 128) ? wl[k * 128 + col] : wr[(k - 128) * 128 + col];
  W2[col * 256 + k] = (short)f2b(v);
}

// ---------------- fused SAGE linear, both sides ------------------------------
// out = act( mean@w_l + x@w_r + b ), all bf16 in/out, fp32 MFMA accum.
__global__ __launch_bounds__(256) void sage_gemm2(
    const unsigned short* __restrict__ agg_u, const unsigned short* __restrict__ x_u,
    const short* __restrict__ W2_u, const float* __restrict__ bias_u,
    unsigned short* __restrict__ out_u,
    const unsigned short* __restrict__ agg_i, const unsigned short* __restrict__ x_i,
    const short* __restrict__ W2_i, const float* __restrict__ bias_i,
    unsigned short* __restrict__ out_i, int relu) {
  const unsigned short *aggb, *xb;
  const short* W2;
  const float* bias;
  unsigned short* outb;
  int N, blk;
  if (blockIdx.x < NBLK_GU) {
    aggb = agg_u; xb = x_u; W2 = W2_u; bias = bias_u; outb = out_u;
    N = U_N; blk = blockIdx.x;
  } else {
    aggb = agg_i; xb = x_i; W2 = W2_i; bias = bias_i; outb = out_i;
    N = I_N; blk = blockIdx.x - NBLK_GU;
  }

  __shared__ short wlds[128 * 256];  // 64 KiB
  const int tid = threadIdx.x;
  for (int c = tid; c < 4096; c += 256) {
    int col = c >> 5, g = c & 31;
    uint4 v = *(const uint4*)(W2 + col * 256 + g * 8);
    *(uint4*)(&wlds[col * 256 + ((g ^ (col & 15)) * 8)]) = v;
  }
  __syncthreads();

  const int lane = tid & 63;
  const int wave = tid >> 6;
  const int q = lane >> 4;
  const int n16 = lane & 15;
  const int rowbase = blk * 128 + wave * 32;

  const unsigned short* aptr[2];
  const unsigned short* xptr[2];
  for (int g = 0; g < 2; ++g) {
    int row = rowbase + g * 16 + n16;
    int rr = row < N ? row : 0;
    aptr[g] = aggb + (size_t)rr * H_DIM + q * 8;
    xptr[g] = xb + (size_t)rr * H_DIM + q * 8;
  }

  f32x4 acc[2][8] = {};

  for (int kt = 0; kt < 8; ++kt) {
    const int k0 = kt * 32;
    bh8 afrag[2];
    for (int g = 0; g < 2; ++g) {
      const unsigned short* p = (kt < 4) ? (aptr[g] + k0) : (xptr[g] + (k0 - 128));
      afrag[g] = *(const bh8*)(p);
    }
    const int swz = ((kt * 4 + q) ^ n16) * 8;
    for (int c = 0; c < 8; ++c) {
      bh8 b = *(const bh8*)(&wlds[(c * 16 + n16) * 256 + swz]);
      acc[0][c] = __builtin_amdgcn_mfma_f32_16x16x32_bf16(afrag[0], b, acc[0][c], 0, 0, 0);
      acc[1][c] = __builtin_amdgcn_mfma_f32_16x16x32_bf16(afrag[1], b, acc[1][c], 0, 0, 0);
    }
  }

  float bcol[8];
  for (int c = 0; c < 8; ++c) bcol[c] = bias[c * 16 + n16];

  for (int g = 0; g < 2; ++g) {
    for (int r = 0; r < 4; ++r) {
      int row = rowbase + g * 16 + q * 4 + r;
      if (row >= N) continue;
      for (int c = 0; c < 8; ++c) {
        float v = acc[g][c][r] + bcol[c];
        if (relu) v = v > 0.0f ? v : 0.0f;
        outb[(size_t)row * H_DIM + c * 16 + n16] = f2b(v);
      }
    }
  }
}

// ---------------- final edge dot product (bf16 h2, 16 lanes/edge) -----------
__global__ __launch_bounds__(256) void final_dot(const int* __restrict__ lbl,
                                                 const unsigned short* __restrict__ u2,
                                                 const unsigned short* __restrict__ i2,
                                                 float* __restrict__ out) {
  long t = (long)blockIdx.x * 256 + threadIdx.x;
  int e = (int)(t >> 4);
  if (e >= EL_N) return;
  int lane = (int)(t & 15);
  int lu = lbl[e];
  int li = lbl[EL_N + e];
  u16x8 a = *(const u16x8*)(u2 + (size_t)lu * H_DIM + lane * 8);
  u16x8 b = *(const u16x8*)(i2 + (size_t)li * H_DIM + lane * 8);
  float p = 0.f;
  for (int k = 0; k < 8; ++k) p += b2f(a[k]) * b2f(b[k]);
  for (int off = 8; off > 0; off >>= 1) p += __shfl_down(p, off, 16);
  if (lane == 0) out[e] = p;
}

extern "C" void kernel_launch(void* const* d_in, const int* in_sizes, int n_in,
                              void* d_out, int out_size, void* d_ws, size_t ws_size,
                              hipStream_t stream) {
  const float* user_emb = (const float*)d_in[0];
  const float* item_emb = (const float*)d_in[1];
  const float* w1_ui_l = (const float*)d_in[2];
  const float* w1_ui_r = (const float*)d_in[3];
  const float* w1_iu_l = (const float*)d_in[4];
  const float* w1_iu_r = (const float*)d_in[5];
  const float* w2_ui_l = (const float*)d_in[6];
  const float* w2_ui_r = (const float*)d_in[7];
  const float* w2_iu_l = (const float*)d_in[8];
  const float* w2_iu_r = (const float*)d_in[9];
  const float* b1_ui = (const float*)d_in[10];
  const float* b1_iu = (const float*)d_in[11];
  const float* b2_ui = (const float*)d_in[12];
  const float* b2_iu = (const float*)d_in[13];
  const int* unid = (const int*)d_in[14];
  const int* inid = (const int*)d_in[15];
  const int* e_ui = (const int*)d_in[16];  // row0 users, row1 items
  const int* e_iu = (const int*)d_in[17];  // row0 items, row1 users
  const int* elbl = (const int*)d_in[18];  // row0 users, row1 items
  float* out = (float*)d_out;

  char* ws = (char*)d_ws;
  size_t o = 0;
  auto alloc = [&](size_t bytes) {
    char* p = ws + o;
    o = (o + bytes + 255) & ~(size_t)255;
    return p;
  };
  int* hist_u = (int*)alloc((size_t)LH_U * 4);
  int* hoff_u = (int*)alloc((size_t)LH_U * 4);
  int* hist_i = (int*)alloc((size_t)LH_I * 4);
  int* hoff_i = (int*)alloc((size_t)LH_I * 4);
  unsigned* bkt_u = (unsigned*)alloc((size_t)E_N * 4);
  unsigned* bkt_i = (unsigned*)alloc((size_t)E_N * 4);
  int* cnt_u = (int*)alloc((size_t)U_N * 4);
  int* cnt_i = (int*)alloc((size_t)I_N * 4);
  int* off_u = (int*)alloc((size_t)U_N * 4);
  int* off_i = (int*)alloc((size_t)I_N * 4);
  int* csr_u = (int*)alloc((size_t)E_N * 4);  // item srcs grouped by user dst
  int* csr_i = (int*)alloc((size_t)E_N * 4);  // user srcs grouped by item dst
  int* bsum_u = (int*)alloc(256 * 4);
  int* bsum_i = (int*)alloc(256 * 4);
  unsigned short* ue_b = (unsigned short*)alloc((size_t)U_N * H_DIM * 2);
  unsigned short* ie_b = (unsigned short*)alloc((size_t)I_N * H_DIM * 2);
  unsigned short* agg_u = (unsigned short*)alloc((size_t)U_N * H_DIM * 2);
  unsigned short* agg_i = (unsigned short*)alloc((size_t)I_N * H_DIM * 2);
  unsigned short* h1_u = (unsigned short*)alloc((size_t)U_N * H_DIM * 2);
  unsigned short* h1_i = (unsigned short*)alloc((size_t)I_N * H_DIM * 2);
  unsigned short* h2_u = (unsigned short*)alloc((size_t)U_N * H_DIM * 2);
  unsigned short* h2_i = (unsigned short*)alloc((size_t)I_N * H_DIM * 2);
  short* W2_1u = (short*)alloc(128 * 256 * 2);
  short* W2_1i = (short*)alloc(128 * 256 * 2);
  short* W2_2u = (short*)alloc(128 * 256 * 2);
  short* W2_2i = (short*)alloc(128 * 256 * 2);
  if (o > ws_size) {
    fprintf(stderr, "kernel_launch: ws too small, need %zu have %zu\n", o, ws_size);
    return;
  }

  // independent prep
  cvt_emb2<<<((U_N + I_N) * 16 + 255) / 256, 256, 0, stream>>>(
      user_emb, item_emb, unid, inid, ue_b, ie_b);
  prep_w4<<<512, 256, 0, stream>>>(w1_iu_l, w1_iu_r, W2_1u,
                                   w1_ui_l, w1_ui_r, W2_1i,
                                   w2_iu_l, w2_iu_r, W2_2u,
                                   w2_ui_l, w2_ui_r, W2_2i);

  // CSR build, atomic-free (global side)
  bin_hist<<<NBLK, 256, 0, stream>>>(e_ui, hist_u, SH_U, NB_U);
  bin_hist<<<NBLK, 256, 0, stream>>>(e_ui + E_N, hist_i, SH_I, NB_I);

  scan_p1<<<(LH_U + 1023) / 1024, 256, 0, stream>>>(hist_u, bsum_u, LH_U);
  scan_p1<<<(LH_I + 1023) / 1024, 256, 0, stream>>>(hist_i, bsum_i, LH_I);
  scan_p2<<<1, 256, 0, stream>>>(bsum_u, (LH_U + 1023) / 1024);
  scan_p2<<<1, 256, 0, stream>>>(bsum_i, (LH_I + 1023) / 1024);
  scan_p3<<<(LH_U + 1023) / 1024, 256, 0, stream>>>(hist_u, bsum_u, hoff_u, LH_U);
  scan_p3<<<(LH_I + 1023) / 1024, 256, 0, stream>>>(hist_i, bsum_i, hoff_i, LH_I);

  bin_scatter<<<NBLK, 256, 0, stream>>>(e_ui, e_ui + E_N, hoff_u, bkt_u, SH_U, NB_U);
  bin_scatter<<<NBLK, 256, 0, stream>>>(e_ui + E_N, e_ui, hoff_i, bkt_i, SH_I, NB_I);

  bin_group<<<NB_U, 256, 0, stream>>>(hoff_u, bkt_u, csr_u, cnt_u, off_u, SH_U, NB_U, U_N);
  bin_group<<<NB_I, 256, 0, stream>>>(hoff_i, bkt_i, csr_i, cnt_i, off_i, SH_I, NB_I, I_N);

  const int g_blocks = ((U_N + I_N) * 16 + 255) / 256;
  // layer 1: users <- items, items <- users
  gather_mean2<<<g_blocks, 256, 0, stream>>>(off_u, cnt_u, csr_u, ie_b, agg_u,
                                             off_i, cnt_i, csr_i, ue_b, agg_i);
  sage_gemm2<<<NBLK_GU + NBLK_GI, 256, 0, stream>>>(
      agg_u, ue_b, W2_1u, b1_iu, h1_u,
      agg_i, ie_b, W2_1i, b1_ui, h1_i, 1);

  // layer 2 (reuse CSR)
  gather_mean2<<<g_blocks, 256, 0, stream>>>(off_u, cnt_u, csr_u, h1_i, agg_u,
                                             off_i, cnt_i, csr_i, h1_u, agg_i);
  sage_gemm2<<<NBLK_GU + NBLK_GI, 256, 0, stream>>>(
      agg_u, h1_u, W2_2u, b2_iu, h2_u,
      agg_i, h1_i, W2_2i, b2_ui, h2_i, 0);

  final_dot<<<(EL_N * 16 + 255) / 256, 256, 0, stream>>>(elbl, h2_u, h2_i, out);
}

// Round 8
// 361.940 us; speedup vs baseline: 12.1514x; 1.0822x over previous
//
#include <hip/hip_runtime.h>
#include <hip/hip_bf16.h>
#include <cstdio>

#define U_N 100000
#define I_N 50000
#define H_DIM 128
#define E_N 600000
#define EL_N 200000

#define EPB 2048                         // edges per block in binning passes
#define NBLK ((E_N + EPB - 1) / EPB)     // 293
#define SH_U 8
#define SH_I 7
#define NB_U ((U_N + 255) >> 8)          // 391
#define NB_I ((I_N + 127) >> 7)          // 391
#define LH_U (NB_U * NBLK)               // 114563
#define LH_I (NB_I * NBLK)
#define LH_TOT (LH_U + LH_I)             // 229126

#define CVT_BLK (((U_N + I_N) * 16) / 256)  // 9375 exact
#define PREP_BLK 512
#define NBU2 ((U_N + 255) / 256)         // 391
#define NBI2 ((I_N + 255) / 256)         // 196

typedef __attribute__((ext_vector_type(8))) short bh8;
typedef __attribute__((ext_vector_type(4))) float f32x4;
typedef __attribute__((ext_vector_type(8))) unsigned short u16x8;

// fp32 -> bf16 (RNE)
__device__ inline unsigned short f2b(float f) {
  unsigned u = __builtin_bit_cast(unsigned, f);
  u += 0x7fffu + ((u >> 16) & 1u);
  return (unsigned short)(u >> 16);
}
// bf16 bits -> fp32
__device__ inline float b2f(unsigned short h) {
  unsigned u = ((unsigned)h) << 16;
  return __builtin_bit_cast(float, u);
}

// ---------------- fused prep: emb convert + weight prep + coarse histogram --
__global__ __launch_bounds__(256) void prep_all(
    const float* __restrict__ xu, const float* __restrict__ xi,
    const int* __restrict__ unid, const int* __restrict__ inid,
    unsigned short* __restrict__ ub, unsigned short* __restrict__ ib,
    const float* __restrict__ l0, const float* __restrict__ r0, short* __restrict__ o0,
    const float* __restrict__ l1, const float* __restrict__ r1, short* __restrict__ o1,
    const float* __restrict__ l2, const float* __restrict__ r2, short* __restrict__ o2,
    const float* __restrict__ l3, const float* __restrict__ r3, short* __restrict__ o3,
    const int* __restrict__ e_ui, int* __restrict__ hist) {
  __shared__ int h[512];
  const int b = blockIdx.x;
  const int tid = threadIdx.x;
  if (b < CVT_BLK) {
    int t = b * 256 + tid;
    const float* x;
    unsigned short* xb;
    int row, seg;
    if (t < U_N * 16) {
      row = t >> 4; seg = t & 15;
      int r0_ = row;
      row = unid ? unid[row] : row;
      x = xu; xb = ub + (size_t)r0_ * H_DIM;
    } else {
      int t2 = t - U_N * 16;
      row = t2 >> 4; seg = t2 & 15;
      int r0_ = row;
      row = inid ? inid[row] : row;
      x = xi; xb = ib + (size_t)r0_ * H_DIM;
    }
    const float* p = x + (size_t)row * H_DIM + seg * 8;
    float4 a = ((const float4*)p)[0];
    float4 c = ((const float4*)p)[1];
    u16x8 v;
    v[0] = f2b(a.x); v[1] = f2b(a.y); v[2] = f2b(a.z); v[3] = f2b(a.w);
    v[4] = f2b(c.x); v[5] = f2b(c.y); v[6] = f2b(c.z); v[7] = f2b(c.w);
    *(u16x8*)(xb + seg * 8) = v;
  } else if (b < CVT_BLK + PREP_BLK) {
    int t = (b - CVT_BLK) * 256 + tid;  // 4*32768
    int set = t >> 15, s = t & 32767;
    const float *wl, *wr; short* W2;
    if (set == 0)      { wl = l0; wr = r0; W2 = o0; }
    else if (set == 1) { wl = l1; wr = r1; W2 = o1; }
    else if (set == 2) { wl = l2; wr = r2; W2 = o2; }
    else               { wl = l3; wr = r3; W2 = o3; }
    int col = s >> 8, k = s & 255;
    float v = (k < 128) ? wl[k * 128 + col] : wr[(k - 128) * 128 + col];
    W2[col * 256 + k] = (short)f2b(v);
  } else {
    int hb = b - CVT_BLK - PREP_BLK;          // [0, 2*NBLK)
    int side = hb >= NBLK;
    int blk = side ? hb - NBLK : hb;
    const int* dst = e_ui + (side ? E_N : 0);
    int shift = side ? SH_I : SH_U;
    int nbins = side ? NB_I : NB_U;
    int hbase = side ? LH_U : 0;
    for (int i = tid; i < nbins; i += 256) h[i] = 0;
    __syncthreads();
    const int base = blk * EPB;
    const int end = min(base + EPB, E_N);
    for (int i = base + tid; i < end; i += 256)
      atomicAdd(&h[((unsigned)dst[i]) >> shift], 1);
    __syncthreads();
    for (int i = tid; i < nbins; i += 256)
      hist[hbase + i * NBLK + blk] = h[i];
  }
}

// ---------------- hierarchical exclusive scan over LH_TOT -------------------
__global__ __launch_bounds__(256) void scan_p1(const int* __restrict__ cnt,
                                               int* __restrict__ bsum, int n) {
  const int t = threadIdx.x;
  const int base = blockIdx.x * 1024 + t * 4;
  int s = 0;
  for (int j = 0; j < 4; ++j) {
    int i = base + j;
    if (i < n) s += cnt[i];
  }
  for (int off = 32; off > 0; off >>= 1) s += __shfl_down(s, off, 64);
  __shared__ int wsum[4];
  if ((t & 63) == 0) wsum[t >> 6] = s;
  __syncthreads();
  if (t == 0) bsum[blockIdx.x] = wsum[0] + wsum[1] + wsum[2] + wsum[3];
}

__global__ __launch_bounds__(256) void scan_p2(int* __restrict__ bsum, int nb) {
  __shared__ int sm[256];
  const int t = threadIdx.x;
  int v = (t < nb) ? bsum[t] : 0;
  sm[t] = v;
  __syncthreads();
  for (int d = 1; d < 256; d <<= 1) {
    int x = (t >= d) ? sm[t - d] : 0;
    __syncthreads();
    sm[t] += x;
    __syncthreads();
  }
  if (t < nb) bsum[t] = sm[t] - v;  // exclusive
}

__global__ __launch_bounds__(256) void scan_p3(const int* __restrict__ cnt,
                                               const int* __restrict__ bsum,
                                               int* __restrict__ off, int n) {
  const int t = threadIdx.x;
  const int lane = t & 63, wv = t >> 6;
  const int base = blockIdx.x * 1024 + t * 4;
  int vals[4];
  int s = 0;
  for (int j = 0; j < 4; ++j) {
    int i = base + j;
    vals[j] = (i < n) ? cnt[i] : 0;
    s += vals[j];
  }
  int inc = s;
  for (int d = 1; d < 64; d <<= 1) {
    int x = __shfl_up(inc, d, 64);
    if (lane >= d) inc += x;
  }
  __shared__ int wsum[4];
  if (lane == 63) wsum[wv] = inc;
  __syncthreads();
  int wbase = 0;
  for (int w = 0; w < wv; ++w) wbase += wsum[w];
  int excl = wbase + (inc - s) + bsum[blockIdx.x];
  for (int j = 0; j < 4; ++j) {
    int i = base + j;
    if (i < n) off[i] = excl;
    excl += vals[j];
  }
}

// ---------------- scatter packed (dstlo|src) into combined buckets ----------
__global__ __launch_bounds__(256) void bin_scatter2(const int* __restrict__ e_ui,
                                                    const int* __restrict__ hoff,
                                                    unsigned* __restrict__ bucketed) {
  __shared__ int cur[512];
  const int t = threadIdx.x;
  const int hb = blockIdx.x;                 // [0, 2*NBLK)
  const int side = hb >= NBLK;
  const int blk = side ? hb - NBLK : hb;
  const int* dst = e_ui + (side ? E_N : 0);
  const int* src = e_ui + (side ? 0 : E_N);
  const int shift = side ? SH_I : SH_U;
  const int nbins = side ? NB_I : NB_U;
  const int hbase = side ? LH_U : 0;
  for (int i = t; i < nbins; i += 256) cur[i] = hoff[hbase + i * NBLK + blk];
  __syncthreads();
  const int base = blk * EPB;
  const int end = min(base + EPB, E_N);
  const unsigned mask = (1u << shift) - 1u;
  for (int i = base + t; i < end; i += 256) {
    unsigned d = (unsigned)dst[i];
    int bin = (int)(d >> shift);
    int pos = atomicAdd(&cur[bin], 1);
    bucketed[pos] = ((d & mask) << 24) | (unsigned)src[i];
  }
}

// ---------------- group bucket by exact dst -> csr (combined), cnt, off -----
__global__ __launch_bounds__(256) void bin_group2(const int* __restrict__ hoff,
                                                  const unsigned* __restrict__ bucketed,
                                                  int* __restrict__ csr,
                                                  int* __restrict__ cnt_u,
                                                  int* __restrict__ off_u,
                                                  int* __restrict__ cnt_i,
                                                  int* __restrict__ off_i) {
  __shared__ int cl[256];
  __shared__ int cur[256];
  __shared__ int wsum[4];
  const int b = blockIdx.x;
  const int t = threadIdx.x;
  const int side = b >= NB_U;
  const int bb = side ? b - NB_U : b;
  const int shift = side ? SH_I : SH_U;
  const int N = side ? I_N : U_N;
  int* cnt = side ? cnt_i : cnt_u;
  int* off = side ? off_i : off_u;
  int start, end;
  if (!side) {
    start = hoff[bb * NBLK];
    end = (bb + 1 < NB_U) ? hoff[(bb + 1) * NBLK] : E_N;
  } else {
    start = hoff[LH_U + bb * NBLK];
    end = (bb + 1 < NB_I) ? hoff[LH_U + (bb + 1) * NBLK] : 2 * E_N;
  }
  const int ndst = 1 << shift;   // 256 (users) or 128 (items)
  const int base = bb << shift;
  if (t < ndst) cl[t] = 0;
  __syncthreads();
  for (int i = start + t; i < end; i += 256)
    atomicAdd(&cl[bucketed[i] >> 24], 1);
  __syncthreads();
  int v = (t < ndst) ? cl[t] : 0;
  const int lane = t & 63, wv = t >> 6;
  int inc = v;
  for (int d = 1; d < 64; d <<= 1) {
    int x = __shfl_up(inc, d, 64);
    if (lane >= d) inc += x;
  }
  if (lane == 63) wsum[wv] = inc;
  __syncthreads();
  int wbase = 0;
  for (int q = 0; q < wv; ++q) wbase += wsum[q];
  int excl = wbase + inc - v;
  if (t < ndst) {
    cur[t] = start + excl;
    int node = base + t;
    if (node < N) { cnt[node] = v; off[node] = start + excl; }
  }
  __syncthreads();
  for (int i = start + t; i < end; i += 256) {
    unsigned w = bucketed[i];
    int pos = atomicAdd(&cur[w >> 24], 1);
    csr[pos] = (int)(w & 0xFFFFFFu);
  }
}

// ---------------- gather-mean, both sides (bf16 in, bf16 mean out) ----------
// 16-lane group per destination node; 16B/lane (u16x8) reads; 8/4/1 ILP ladder.
__global__ __launch_bounds__(256) void gather_mean2(
    const int* __restrict__ off_u, const int* __restrict__ cnt_u,
    const unsigned short* __restrict__ xsrc_u, unsigned short* __restrict__ agg_u,
    const int* __restrict__ off_i, const int* __restrict__ cnt_i,
    const unsigned short* __restrict__ xsrc_i, unsigned short* __restrict__ agg_i,
    const int* __restrict__ csr) {
  long t = (long)blockIdx.x * 256 + threadIdx.x;
  int node = (int)(t >> 4);
  int lane = (int)(t & 15);
  const int* off; const int* cnt;
  const unsigned short* xb; unsigned short* aggb;
  if (node < U_N) {
    off = off_u; cnt = cnt_u; xb = xsrc_u; aggb = agg_u;
  } else {
    node -= U_N;
    if (node >= I_N) return;
    off = off_i; cnt = cnt_i; xb = xsrc_i; aggb = agg_i;
  }
  int o = off[node], c = cnt[node];
  float acc[8] = {};
  for (int j0 = 0; j0 < c; j0 += 16) {
    int nj = c - j0;
    if (nj > 16) nj = 16;
    int sidx = (lane < nj) ? csr[o + j0 + lane] : 0;
    int j = 0;
    for (; j + 8 <= nj; j += 8) {
      u16x8 v[8];
      for (int m = 0; m < 8; ++m) {
        int s = __shfl(sidx, j + m, 16);
        v[m] = *(const u16x8*)(xb + (size_t)s * H_DIM + lane * 8);
      }
      for (int m = 0; m < 8; ++m)
        for (int k = 0; k < 8; ++k) acc[k] += b2f(v[m][k]);
    }
    for (; j + 4 <= nj; j += 4) {
      u16x8 v[4];
      for (int m = 0; m < 4; ++m) {
        int s = __shfl(sidx, j + m, 16);
        v[m] = *(const u16x8*)(xb + (size_t)s * H_DIM + lane * 8);
      }
      for (int m = 0; m < 4; ++m)
        for (int k = 0; k < 8; ++k) acc[k] += b2f(v[m][k]);
    }
    for (; j < nj; ++j) {
      int s = __shfl(sidx, j, 16);
      u16x8 v = *(const u16x8*)(xb + (size_t)s * H_DIM + lane * 8);
      for (int k = 0; k < 8; ++k) acc[k] += b2f(v[k]);
    }
  }
  float inv = 1.0f / (float)(c > 0 ? c : 1);
  u16x8 r;
  for (int k = 0; k < 8; ++k) r[k] = f2b(acc[k] * inv);
  *(u16x8*)(aggb + (size_t)node * H_DIM + lane * 8) = r;
}

// ---------------- fused SAGE linear, both sides, 256 rows/block --------------
// out = act( mean@w_l + x@w_r + b ), all bf16 in/out, fp32 MFMA accum.
__global__ __launch_bounds__(256, 2) void sage_gemm2(
    const unsigned short* __restrict__ agg_u, const unsigned short* __restrict__ x_u,
    const short* __restrict__ W2_u, const float* __restrict__ bias_u,
    unsigned short* __restrict__ out_u,
    const unsigned short* __restrict__ agg_i, const unsigned short* __restrict__ x_i,
    const short* __restrict__ W2_i, const float* __restrict__ bias_i,
    unsigned short* __restrict__ out_i, int relu) {
  const unsigned short *aggb, *xb;
  const short* W2;
  const float* bias;
  unsigned short* outb;
  int N, blk;
  if (blockIdx.x < NBU2) {
    aggb = agg_u; xb = x_u; W2 = W2_u; bias = bias_u; outb = out_u;
    N = U_N; blk = blockIdx.x;
  } else {
    aggb = agg_i; xb = x_i; W2 = W2_i; bias = bias_i; outb = out_i;
    N = I_N; blk = blockIdx.x - NBU2;
  }

  __shared__ short wlds[128 * 256];  // 64 KiB
  const int tid = threadIdx.x;
  for (int c = tid; c < 4096; c += 256) {
    int col = c >> 5, g = c & 31;
    uint4 v = *(const uint4*)(W2 + col * 256 + g * 8);
    *(uint4*)(&wlds[col * 256 + ((g ^ (col & 15)) * 8)]) = v;
  }
  __syncthreads();

  const int lane = tid & 63;
  const int wave = tid >> 6;
  const int q = lane >> 4;
  const int n16 = lane & 15;
  const int rowbase = blk * 256 + wave * 64;

  const unsigned short* aptr[4];
  const unsigned short* xptr[4];
  for (int g = 0; g < 4; ++g) {
    int row = rowbase + g * 16 + n16;
    int rr = row < N ? row : 0;
    aptr[g] = aggb + (size_t)rr * H_DIM + q * 8;
    xptr[g] = xb + (size_t)rr * H_DIM + q * 8;
  }

  f32x4 acc[4][8] = {};

  for (int kt = 0; kt < 8; ++kt) {
    const int k0 = kt * 32;
    bh8 afrag[4];
    for (int g = 0; g < 4; ++g) {
      const unsigned short* p = (kt < 4) ? (aptr[g] + k0) : (xptr[g] + (k0 - 128));
      afrag[g] = *(const bh8*)(p);
    }
    const int swz = ((kt * 4 + q) ^ n16) * 8;
    for (int c = 0; c < 8; ++c) {
      bh8 b = *(const bh8*)(&wlds[(c * 16 + n16) * 256 + swz]);
      acc[0][c] = __builtin_amdgcn_mfma_f32_16x16x32_bf16(afrag[0], b, acc[0][c], 0, 0, 0);
      acc[1][c] = __builtin_amdgcn_mfma_f32_16x16x32_bf16(afrag[1], b, acc[1][c], 0, 0, 0);
      acc[2][c] = __builtin_amdgcn_mfma_f32_16x16x32_bf16(afrag[2], b, acc[2][c], 0, 0, 0);
      acc[3][c] = __builtin_amdgcn_mfma_f32_16x16x32_bf16(afrag[3], b, acc[3][c], 0, 0, 0);
    }
  }

  float bcol[8];
  for (int c = 0; c < 8; ++c) bcol[c] = bias[c * 16 + n16];

  for (int g = 0; g < 4; ++g) {
    for (int r = 0; r < 4; ++r) {
      int row = rowbase + g * 16 + q * 4 + r;
      if (row >= N) continue;
      for (int c = 0; c < 8; ++c) {
        float v = acc[g][c][r] + bcol[c];
        if (relu) v = v > 0.0f ? v : 0.0f;
        outb[(size_t)row * H_DIM + c * 16 + n16] = f2b(v);
      }
    }
  }
}

// ---------------- final edge dot product (bf16 h2, 16 lanes/edge) -----------
__global__ __launch_bounds__(256) void final_dot(const int* __restrict__ lbl,
                                                 const unsigned short* __restrict__ u2,
                                                 const unsigned short* __restrict__ i2,
                                                 float* __restrict__ out) {
  long t = (long)blockIdx.x * 256 + threadIdx.x;
  int e = (int)(t >> 4);
  if (e >= EL_N) return;
  int lane = (int)(t & 15);
  int lu = lbl[e];
  int li = lbl[EL_N + e];
  u16x8 a = *(const u16x8*)(u2 + (size_t)lu * H_DIM + lane * 8);
  u16x8 b = *(const u16x8*)(i2 + (size_t)li * H_DIM + lane * 8);
  float p = 0.f;
  for (int k = 0; k < 8; ++k) p += b2f(a[k]) * b2f(b[k]);
  for (int off = 8; off > 0; off >>= 1) p += __shfl_down(p, off, 16);
  if (lane == 0) out[e] = p;
}

extern "C" void kernel_launch(void* const* d_in, const int* in_sizes, int n_in,
                              void* d_out, int out_size, void* d_ws, size_t ws_size,
                              hipStream_t stream) {
  const float* user_emb = (const float*)d_in[0];
  const float* item_emb = (const float*)d_in[1];
  const float* w1_ui_l = (const float*)d_in[2];
  const float* w1_ui_r = (const float*)d_in[3];
  const float* w1_iu_l = (const float*)d_in[4];
  const float* w1_iu_r = (const float*)d_in[5];
  const float* w2_ui_l = (const float*)d_in[6];
  const float* w2_ui_r = (const float*)d_in[7];
  const float* w2_iu_l = (const float*)d_in[8];
  const float* w2_iu_r = (const float*)d_in[9];
  const float* b1_ui = (const float*)d_in[10];
  const float* b1_iu = (const float*)d_in[11];
  const float* b2_ui = (const float*)d_in[12];
  const float* b2_iu = (const float*)d_in[13];
  const int* unid = (const int*)d_in[14];
  const int* inid = (const int*)d_in[15];
  const int* e_ui = (const int*)d_in[16];  // row0 users, row1 items
  const int* e_iu = (const int*)d_in[17];  // row0 items, row1 users
  const int* elbl = (const int*)d_in[18];  // row0 users, row1 items
  float* out = (float*)d_out;

  char* ws = (char*)d_ws;
  size_t o = 0;
  auto alloc = [&](size_t bytes) {
    char* p = ws + o;
    o = (o + bytes + 255) & ~(size_t)255;
    return p;
  };
  int* hist = (int*)alloc((size_t)LH_TOT * 4);
  int* hoff = (int*)alloc((size_t)LH_TOT * 4);
  unsigned* bkt = (unsigned*)alloc((size_t)2 * E_N * 4);
  int* csr = (int*)alloc((size_t)2 * E_N * 4);   // u-region [0,E_N), i-region [E_N,2E_N)
  int* cnt_u = (int*)alloc((size_t)U_N * 4);
  int* cnt_i = (int*)alloc((size_t)I_N * 4);
  int* off_u = (int*)alloc((size_t)U_N * 4);
  int* off_i = (int*)alloc((size_t)I_N * 4);
  int* bsum = (int*)alloc(256 * 4);
  unsigned short* ue_b = (unsigned short*)alloc((size_t)U_N * H_DIM * 2);
  unsigned short* ie_b = (unsigned short*)alloc((size_t)I_N * H_DIM * 2);
  unsigned short* agg_u = (unsigned short*)alloc((size_t)U_N * H_DIM * 2);
  unsigned short* agg_i = (unsigned short*)alloc((size_t)I_N * H_DIM * 2);
  unsigned short* h1_u = (unsigned short*)alloc((size_t)U_N * H_DIM * 2);
  unsigned short* h1_i = (unsigned short*)alloc((size_t)I_N * H_DIM * 2);
  unsigned short* h2_u = (unsigned short*)alloc((size_t)U_N * H_DIM * 2);
  unsigned short* h2_i = (unsigned short*)alloc((size_t)I_N * H_DIM * 2);
  short* W2_1u = (short*)alloc(128 * 256 * 2);
  short* W2_1i = (short*)alloc(128 * 256 * 2);
  short* W2_2u = (short*)alloc(128 * 256 * 2);
  short* W2_2i = (short*)alloc(128 * 256 * 2);
  if (o > ws_size) {
    fprintf(stderr, "kernel_launch: ws too small, need %zu have %zu\n", o, ws_size);
    return;
  }

  // 1) fused prep: cvt + weights + coarse histogram
  prep_all<<<CVT_BLK + PREP_BLK + 2 * NBLK, 256, 0, stream>>>(
      user_emb, item_emb, unid, inid, ue_b, ie_b,
      w1_iu_l, w1_iu_r, W2_1u, w1_ui_l, w1_ui_r, W2_1i,
      w2_iu_l, w2_iu_r, W2_2u, w2_ui_l, w2_ui_r, W2_2i,
      e_ui, hist);

  // 2-4) scan of concatenated histogram
  const int nb1 = (LH_TOT + 1023) / 1024;  // 224
  scan_p1<<<nb1, 256, 0, stream>>>(hist, bsum, LH_TOT);
  scan_p2<<<1, 256, 0, stream>>>(bsum, nb1);
  scan_p3<<<nb1, 256, 0, stream>>>(hist, bsum, hoff, LH_TOT);

  // 5) scatter into combined buckets, 6) group -> combined csr + cnt/off
  bin_scatter2<<<2 * NBLK, 256, 0, stream>>>(e_ui, hoff, bkt);
  bin_group2<<<NB_U + NB_I, 256, 0, stream>>>(hoff, bkt, csr, cnt_u, off_u, cnt_i, off_i);

  const int g_blocks = ((U_N + I_N) * 16 + 255) / 256;
  // 7-8) layer 1
  gather_mean2<<<g_blocks, 256, 0, stream>>>(off_u, cnt_u, ie_b, agg_u,
                                             off_i, cnt_i, ue_b, agg_i, csr);
  sage_gemm2<<<NBU2 + NBI2, 256, 0, stream>>>(
      agg_u, ue_b, W2_1u, b1_iu, h1_u,
      agg_i, ie_b, W2_1i, b1_ui, h1_i, 1);

  // 9-10) layer 2 (reuse CSR)
  gather_mean2<<<g_blocks, 256, 0, stream>>>(off_u, cnt_u, h1_i, agg_u,
                                             off_i, cnt_i, h1_u, agg_i, csr);
  sage_gemm2<<<NBU2 + NBI2, 256, 0, stream>>>(
      agg_u, h1_u, W2_2u, b2_iu, h2_u,
      agg_i, h1_i, W2_2i, b2_ui, h2_i, 0);

  // 11) classifier
  final_dot<<<(EL_N * 16 + 255) / 256, 256, 0, stream>>>(elbl, h2_u, h2_i, out);
}